// Round 6
// baseline (762.341 us; speedup 1.0000x reference)
//
#include <hip/hip_runtime.h>

#define DIM 128
#define NT 256
#define BUCK 64          // dst nodes per bucket
#define PCH 4096         // edges per partition chunk
#define NBMAX 1024       // max buckets supported (n <= 65536)
#define BAT 512          // threads in bucket_aggregate

typedef __attribute__((ext_vector_type(8))) short short8;
typedef __attribute__((ext_vector_type(8))) unsigned short ushort8;
typedef __attribute__((ext_vector_type(4))) float f32x4;

static __device__ __forceinline__ unsigned short f32_to_bf16(float f) {
    union { float f; unsigned int u; } c; c.f = f;
    unsigned int u = c.u;
    u += 0x7FFFu + ((u >> 16) & 1u);   // RNE
    return (unsigned short)(u >> 16);
}
static __device__ __forceinline__ float bf16lo_to_f32(unsigned int v) {
    union { unsigned int u; float f; } c; c.u = v << 16; return c.f;
}
static __device__ __forceinline__ float bf16hi_to_f32(unsigned int v) {
    union { unsigned int u; float f; } c; c.u = v & 0xFFFF0000u; return c.f;
}

// x (f32) -> x_bf (bf16), float4 per thread.
__global__ void prepx_kernel(const float* __restrict__ x, unsigned short* __restrict__ xb, int n4) {
    int g = blockIdx.x * blockDim.x + threadIdx.x;
    if (g >= n4) return;
    float4 v = reinterpret_cast<const float4*>(x)[g];
    ushort4 s = make_ushort4(f32_to_bf16(v.x), f32_to_bf16(v.y), f32_to_bf16(v.z), f32_to_bf16(v.w));
    reinterpret_cast<ushort4*>(xb)[g] = s;
}

// Bucket histogram, LDS-staged (796 global atomics per block instead of 800k total).
__global__ void bhist_kernel(const int* __restrict__ ei, int* __restrict__ bcnt, int E, int NB) {
    __shared__ int h[NBMAX];
    for (int i = threadIdx.x; i < NB; i += blockDim.x) h[i] = 0;
    __syncthreads();
    for (int e = blockIdx.x * blockDim.x + threadIdx.x; e < E; e += gridDim.x * blockDim.x)
        atomicAdd(&h[ei[E + e] >> 6], 1);
    __syncthreads();
    for (int i = threadIdx.x; i < NB; i += blockDim.x)
        if (h[i]) atomicAdd(&bcnt[i], h[i]);
}

// Single-block scan over NB (<=1024) buckets.
__global__ void bscan_kernel(const int* __restrict__ bcnt, int* __restrict__ boffs,
                             int* __restrict__ bcursor, int NB, int E) {
    __shared__ int sh[NBMAX];
    int t = threadIdx.x;
    int v = (t < NB) ? bcnt[t] : 0;
    sh[t] = v;
    __syncthreads();
    for (int d = 1; d < NBMAX; d <<= 1) {
        int u = (t >= d) ? sh[t - d] : 0;
        __syncthreads();
        sh[t] += u;
        __syncthreads();
    }
    if (t < NB) { int o = sh[t] - v; boffs[t] = o; bcursor[t] = o; }
    if (t == 0) boffs[NB] = E;
}

// Chunk-local partition: per-block LDS histogram -> one cursor reservation per
// bucket -> scatter packed (dst<<16 | src) in contiguous per-bucket runs.
__global__ void partition_kernel(const int* __restrict__ ei, int* __restrict__ bcursor,
                                 unsigned int* __restrict__ csr, int E, int NB) {
    __shared__ int hist[NBMAX];
    __shared__ int wbase[NBMAX];
    __shared__ int lcur[NBMAX];
    int t = threadIdx.x;
    int cbase = blockIdx.x * PCH;
    int cend = min(E, cbase + PCH);
    for (int i = t; i < NB; i += NT) { hist[i] = 0; lcur[i] = 0; }
    __syncthreads();
    for (int e = cbase + t; e < cend; e += NT)
        atomicAdd(&hist[ei[E + e] >> 6], 1);
    __syncthreads();
    for (int b = t; b < NB; b += NT) {
        int c = hist[b];
        wbase[b] = c ? atomicAdd(&bcursor[b], c) : 0;
    }
    __syncthreads();
    for (int e = cbase + t; e < cend; e += NT) {
        unsigned int src = (unsigned int)ei[e];
        unsigned int dst = (unsigned int)ei[E + e];
        int b = (int)(dst >> 6);
        int r = atomicAdd(&lcur[b], 1);
        csr[wbase[b] + r] = (dst << 16) | src;
    }
}

// One block per bucket: 64x128 f32 LDS accumulator, conflict-free ds_add_f32
// (acc slot l holds elem 2l, slot 64+l holds elem 2l+1 -> bank = l&31, 2-way = free).
// Degree counted in LDS; mean written coalesced (bf16 if MEANBF else f32 to out).
template <int MEANBF>
__global__ void bucket_aggregate_kernel(const unsigned short* __restrict__ xb,
                                        const int* __restrict__ boffs,
                                        const unsigned int* __restrict__ csr,
                                        float* __restrict__ meanf,
                                        unsigned short* __restrict__ meanb,
                                        int n) {
    __shared__ float acc[BUCK * DIM];
    __shared__ int ldeg[BUCK];
    for (int i = threadIdx.x; i < BUCK * DIM; i += BAT) acc[i] = 0.f;
    for (int i = threadIdx.x; i < BUCK; i += BAT) ldeg[i] = 0;
    __syncthreads();

    int b0 = blockIdx.x;
    int start = boffs[b0], end = boffs[b0 + 1];
    int wid = threadIdx.x >> 6, lane = threadIdx.x & 63;
    const int nw = BAT >> 6;   // 8 waves
    const unsigned int* xu = reinterpret_cast<const unsigned int*>(xb);

    // 2-wide unrolled wave loop: pairs (e, e+1) strided by 2*nw across waves.
    for (int e = start + wid * 2; e < end; e += nw * 2) {
        unsigned int p0 = csr[e];                       // wave-uniform broadcast
        int has2 = (e + 1 < end);
        unsigned int p1 = has2 ? csr[e + 1] : p0;
        int s0 = (int)(p0 & 0xFFFFu), d0 = (int)((p0 >> 16) & 63u);
        int s1 = (int)(p1 & 0xFFFFu), d1 = (int)((p1 >> 16) & 63u);
        unsigned int v0 = xu[(size_t)s0 * 64 + lane];   // 256B coalesced gather
        unsigned int v1 = has2 ? xu[(size_t)s1 * 64 + lane] : 0u;
        atomicAdd(&acc[d0 * DIM + lane], bf16lo_to_f32(v0));
        atomicAdd(&acc[d0 * DIM + 64 + lane], bf16hi_to_f32(v0));
        if (has2) {
            atomicAdd(&acc[d1 * DIM + lane], bf16lo_to_f32(v1));
            atomicAdd(&acc[d1 * DIM + 64 + lane], bf16hi_to_f32(v1));
        }
        if (lane == 0) {
            atomicAdd(&ldeg[d0], 1);
            if (has2) atomicAdd(&ldeg[d1], 1);
        }
    }
    __syncthreads();

    int gbase = b0 * BUCK;
    for (int idx = threadIdx.x; idx < BUCK * 64; idx += BAT) {
        int node = idx >> 6, c = idx & 63;
        int gnode = gbase + node;
        if (gnode >= n) continue;
        int d = ldeg[node];
        float inv = (d > 0) ? 1.0f / (float)d : 0.f;
        float lo = acc[node * DIM + c] * inv;        // elem 2c
        float hi = acc[node * DIM + 64 + c] * inv;   // elem 2c+1
        if (MEANBF) {
            unsigned int pk = (unsigned int)f32_to_bf16(lo) | ((unsigned int)f32_to_bf16(hi) << 16);
            reinterpret_cast<unsigned int*>(meanb)[(size_t)gnode * 64 + c] = pk;
        } else {
            meanf[(size_t)gnode * DIM + 2 * c] = lo;
            meanf[(size_t)gnode * DIM + 2 * c + 1] = hi;
        }
    }
}

// Prep: pack W_B into bf16 MFMA B-fragment order + combined bias.
__global__ void prep_kernel(const float* __restrict__ w_self, const float* __restrict__ b_self,
                            const float* __restrict__ w_neigh, const float* __restrict__ b_neigh,
                            unsigned short* __restrict__ w_swz, float* __restrict__ bias) {
    int g = blockIdx.x * blockDim.x + threadIdx.x;
    if (g < 128) bias[g] = b_self[g] + b_neigh[g];
    if (g >= 64 * 64) return;
    int f = g >> 6, l = g & 63;
    int ks = f >> 3, nf = f & 7;
    int j = nf * 16 + (l & 15);
    int kbase = ks * 32 + ((l >> 4) << 3);
#pragma unroll
    for (int e = 0; e < 8; ++e) {
        int k = kbase + e;
        float v = (k < 128) ? w_self[(size_t)j * 128 + k] : w_neigh[(size_t)j * 128 + (k - 128)];
        w_swz[((size_t)g << 3) + e] = f32_to_bf16(v);
    }
}

// MFMA finalize: out = [x|mean]_bf16 @ W_B + bias.
#define FROWS 64
template <int MEANBF>
__global__ void finalize_kernel(const unsigned short* __restrict__ xb,
                                const float* __restrict__ meanf,
                                const unsigned short* __restrict__ meanb,
                                const unsigned short* __restrict__ w_swz,
                                const float* __restrict__ bias,
                                float* __restrict__ out, int n) {
    __shared__ unsigned short xm[FROWS][264];   // stride 132 dw -> 2-way max (free)
    int t = threadIdx.x;
    int base = blockIdx.x * FROWS;

    if (MEANBF) {
        for (int fi = t; fi < FROWS * 32; fi += NT) {
            int row = fi >> 5, c = fi & 31;
            int grow = base + row;
            ushort8 s = (ushort8)0;
            if (grow < n) {
                s = (c < 16)
                  ? reinterpret_cast<const ushort8*>(xb + (size_t)grow * DIM)[c]
                  : reinterpret_cast<const ushort8*>(meanb + (size_t)grow * DIM)[c - 16];
            }
            *reinterpret_cast<ushort8*>(&xm[row][c * 8]) = s;
        }
    } else {
        for (int fi = t; fi < FROWS * 16; fi += NT) {
            int row = fi >> 4, c = fi & 15;
            int grow = base + row;
            ushort8 s = (ushort8)0;
            if (grow < n) s = reinterpret_cast<const ushort8*>(xb + (size_t)grow * DIM)[c];
            *reinterpret_cast<ushort8*>(&xm[row][c * 8]) = s;
        }
        for (int fi = t; fi < FROWS * 32; fi += NT) {
            int row = fi >> 5, c4 = fi & 31;
            int grow = base + row;
            ushort4 sm = {0, 0, 0, 0};
            if (grow < n) {
                float4 mv = reinterpret_cast<const float4*>(meanf + (size_t)grow * DIM)[c4];
                sm = make_ushort4(f32_to_bf16(mv.x), f32_to_bf16(mv.y), f32_to_bf16(mv.z), f32_to_bf16(mv.w));
            }
            *reinterpret_cast<ushort4*>(&xm[row][128 + c4 * 4]) = sm;
        }
    }
    __syncthreads();

    int wave = t >> 6, lane = t & 63;
    int wrow = wave * 16;
    int arow = wrow + (lane & 15);
    int koff = (lane >> 4) << 3;

    f32x4 acc[8];
#pragma unroll
    for (int nf = 0; nf < 8; ++nf) acc[nf] = (f32x4){0.f, 0.f, 0.f, 0.f};

#pragma unroll
    for (int ks = 0; ks < 8; ++ks) {
        short8 a = *reinterpret_cast<const short8*>(&xm[arow][ks * 32 + koff]);
#pragma unroll
        for (int nf = 0; nf < 8; ++nf) {
            short8 b = *reinterpret_cast<const short8*>(
                w_swz + ((((size_t)ks * 8 + nf) * 64 + lane) << 3));
            acc[nf] = __builtin_amdgcn_mfma_f32_16x16x32_bf16(a, b, acc[nf], 0, 0, 0);
        }
    }

    int crow0 = wrow + ((lane >> 4) << 2);
#pragma unroll
    for (int nf = 0; nf < 8; ++nf) {
        int col = nf * 16 + (lane & 15);
        float bs = bias[col];
#pragma unroll
        for (int r = 0; r < 4; ++r) {
            int grow = base + crow0 + r;
            if (grow < n) out[(size_t)grow * DIM + col] = acc[nf][r] + bs;
        }
    }
}

extern "C" void kernel_launch(void* const* d_in, const int* in_sizes, int n_in,
                              void* d_out, int out_size, void* d_ws, size_t ws_size,
                              hipStream_t stream) {
    const float* x       = (const float*)d_in[0];
    const int*   ei      = (const int*)d_in[1];
    const float* w_self  = (const float*)d_in[2];
    const float* b_self  = (const float*)d_in[3];
    const float* w_neigh = (const float*)d_in[4];
    const float* b_neigh = (const float*)d_in[5];
    float* out = (float*)d_out;

    int n = in_sizes[0] / DIM;
    int E = in_sizes[1] / 2;
    int NB = (n + BUCK - 1) / BUCK;   // 782 for n=50000; requires NB <= NBMAX

    // ws: bcnt[NBMAX] | boffs[NBMAX+1] | bcursor[NBMAX] | csr uint[E] |
    //     (align16) w_swz bf16[32768] | bias f32[128] | x_bf bf16[n*128] | mean_bf bf16[n*128]
    int* bcnt    = (int*)d_ws;
    int* boffs   = bcnt + NBMAX;
    int* bcursor = boffs + NBMAX + 1;
    unsigned int* csr = (unsigned int*)(bcursor + NBMAX);
    unsigned short* w_swz = (unsigned short*)(((uintptr_t)(csr + E) + 15) & ~(uintptr_t)15);
    float* bias = (float*)(w_swz + 64 * 64 * 8);
    unsigned short* x_bf = (unsigned short*)(bias + 128);
    unsigned short* mean_bf = x_bf + (size_t)n * DIM;
    size_t need_full = (size_t)((char*)(mean_bf + (size_t)n * DIM) - (char*)d_ws);
    bool meanbf = ws_size >= need_full;

    hipMemsetAsync(bcnt, 0, (size_t)NB * sizeof(int), stream);

    prep_kernel<<<16, 256, 0, stream>>>(w_self, b_self, w_neigh, b_neigh, w_swz, bias);
    int n4 = n * DIM / 4;
    prepx_kernel<<<(n4 + NT - 1) / NT, NT, 0, stream>>>(x, x_bf, n4);

    int pblocks = (E + PCH - 1) / PCH;   // 196
    bhist_kernel<<<pblocks, NT, 0, stream>>>(ei, bcnt, E, NB);
    bscan_kernel<<<1, NBMAX, 0, stream>>>(bcnt, boffs, bcursor, NB, E);
    partition_kernel<<<pblocks, NT, 0, stream>>>(ei, bcursor, csr, E, NB);

    int fblocks = (n + FROWS - 1) / FROWS;
    if (meanbf) {
        bucket_aggregate_kernel<1><<<NB, BAT, 0, stream>>>(x_bf, boffs, csr, nullptr, mean_bf, n);
        finalize_kernel<1><<<fblocks, NT, 0, stream>>>(x_bf, nullptr, mean_bf, w_swz, bias, out, n);
    } else {
        bucket_aggregate_kernel<0><<<NB, BAT, 0, stream>>>(x_bf, boffs, csr, out, nullptr, n);
        finalize_kernel<0><<<fblocks, NT, 0, stream>>>(x_bf, out, nullptr, w_swz, bias, out, n);
    }
}

// Round 7
// 134.864 us; speedup vs baseline: 5.6527x; 5.6527x over previous
//
#include <hip/hip_runtime.h>

#define DIM 128
#define NT 256
#define BUCK 64          // dst nodes per bucket
#define PCH 8192         // edges per partition chunk
#define NBMAX 1024       // max buckets supported (n <= 65536)
#define BAT 512          // threads in bucket_aggregate (8 waves x 8 nodes)
#define CAP 2048         // edges per aggregate sort chunk

typedef __attribute__((ext_vector_type(8))) short short8;
typedef __attribute__((ext_vector_type(8))) unsigned short ushort8;
typedef __attribute__((ext_vector_type(4))) float f32x4;

static __device__ __forceinline__ unsigned short f32_to_bf16(float f) {
    union { float f; unsigned int u; } c; c.f = f;
    unsigned int u = c.u;
    u += 0x7FFFu + ((u >> 16) & 1u);   // RNE
    return (unsigned short)(u >> 16);
}
static __device__ __forceinline__ float bf16lo_to_f32(unsigned int v) {
    union { unsigned int u; float f; } c; c.u = v << 16; return c.f;
}
static __device__ __forceinline__ float bf16hi_to_f32(unsigned int v) {
    union { unsigned int u; float f; } c; c.u = v & 0xFFFF0000u; return c.f;
}

// x (f32) -> x_bf (bf16), float4 per thread.
__global__ void prepx_kernel(const float* __restrict__ x, unsigned short* __restrict__ xb, int n4) {
    int g = blockIdx.x * blockDim.x + threadIdx.x;
    if (g >= n4) return;
    float4 v = reinterpret_cast<const float4*>(x)[g];
    ushort4 s = make_ushort4(f32_to_bf16(v.x), f32_to_bf16(v.y), f32_to_bf16(v.z), f32_to_bf16(v.w));
    reinterpret_cast<ushort4*>(xb)[g] = s;
}

// Bucket histogram, LDS-staged.
__global__ void bhist_kernel(const int* __restrict__ ei, int* __restrict__ bcnt, int E, int NB) {
    __shared__ int h[NBMAX];
    for (int i = threadIdx.x; i < NB; i += blockDim.x) h[i] = 0;
    __syncthreads();
    for (int e = blockIdx.x * blockDim.x + threadIdx.x; e < E; e += gridDim.x * blockDim.x)
        atomicAdd(&h[ei[E + e] >> 6], 1);
    __syncthreads();
    for (int i = threadIdx.x; i < NB; i += blockDim.x)
        if (h[i]) atomicAdd(&bcnt[i], h[i]);
}

// Single-block scan over NB (<=1024) buckets.
__global__ void bscan_kernel(const int* __restrict__ bcnt, int* __restrict__ boffs,
                             int* __restrict__ bcursor, int NB, int E) {
    __shared__ int sh[NBMAX];
    int t = threadIdx.x;
    int v = (t < NB) ? bcnt[t] : 0;
    sh[t] = v;
    __syncthreads();
    for (int d = 1; d < NBMAX; d <<= 1) {
        int u = (t >= d) ? sh[t - d] : 0;
        __syncthreads();
        sh[t] += u;
        __syncthreads();
    }
    if (t < NB) { int o = sh[t] - v; boffs[t] = o; bcursor[t] = o; }
    if (t == 0) boffs[NB] = E;
}

// Chunk-local partition: LDS histogram -> one cursor reservation per bucket ->
// scatter packed (dst<<16 | src) in contiguous per-bucket runs.
__global__ void partition_kernel(const int* __restrict__ ei, int* __restrict__ bcursor,
                                 unsigned int* __restrict__ csr, int E, int NB) {
    __shared__ int hist[NBMAX];
    __shared__ int wbase[NBMAX];
    __shared__ int lcur[NBMAX];
    int t = threadIdx.x;
    int cbase = blockIdx.x * PCH;
    int cend = min(E, cbase + PCH);
    for (int i = t; i < NB; i += NT) { hist[i] = 0; lcur[i] = 0; }
    __syncthreads();
    for (int e = cbase + t; e < cend; e += NT)
        atomicAdd(&hist[ei[E + e] >> 6], 1);
    __syncthreads();
    for (int b = t; b < NB; b += NT) {
        int c = hist[b];
        wbase[b] = c ? atomicAdd(&bcursor[b], c) : 0;
    }
    __syncthreads();
    for (int e = cbase + t; e < cend; e += NT) {
        unsigned int src = (unsigned int)ei[e];
        unsigned int dst = (unsigned int)ei[E + e];
        int b = (int)(dst >> 6);
        int r = atomicAdd(&lcur[b], 1);
        csr[wbase[b] + r] = (dst << 16) | src;
    }
}

// One block per bucket. Per 2048-edge chunk: LDS counting-sort by local dst
// (int atomics only), then wave w accumulates nodes 8w..8w+7 in REGISTERS
// (float2 per lane, 4 gathers in flight) — no f32 LDS atomics anywhere.
template <int MEANBF>
__global__ void bucket_aggregate_kernel(const unsigned short* __restrict__ xb,
                                        const int* __restrict__ boffs,
                                        const unsigned int* __restrict__ csr,
                                        float* __restrict__ meanf,
                                        unsigned short* __restrict__ meanb,
                                        int n) {
    __shared__ unsigned int raw[CAP];
    __shared__ int srt[CAP];
    __shared__ int bin[BUCK];
    __shared__ int boff_s[BUCK + 1];
    __shared__ int cur[BUCK];
    int tid = threadIdx.x, wid = tid >> 6, lane = tid & 63;
    int b0 = blockIdx.x;
    int start = boffs[b0], end = boffs[b0 + 1];
    const unsigned int* xu = reinterpret_cast<const unsigned int*>(xb);

    float ax[8], ay[8];
    int dg[8];
#pragma unroll
    for (int i = 0; i < 8; ++i) { ax[i] = 0.f; ay[i] = 0.f; dg[i] = 0; }

    for (int cb = start; cb < end; cb += CAP) {
        int cnt = min(CAP, end - cb);
        for (int i = tid; i < cnt; i += BAT) raw[i] = csr[cb + i];
        for (int i = tid; i < BUCK; i += BAT) bin[i] = 0;
        __syncthreads();
        for (int i = tid; i < cnt; i += BAT) atomicAdd(&bin[(raw[i] >> 16) & 63], 1);
        __syncthreads();
        if (wid == 0) {   // wave-0 shuffle scan of 64 bins
            int v = bin[lane];
            int s = v;
            for (int d = 1; d < 64; d <<= 1) {
                int u = __shfl_up(s, d, 64);
                if (lane >= d) s += u;
            }
            boff_s[lane] = s - v;
            cur[lane] = s - v;
            if (lane == 63) boff_s[64] = s;
        }
        __syncthreads();
        for (int i = tid; i < cnt; i += BAT) {
            unsigned int p = raw[i];
            int d = (p >> 16) & 63;
            int pos = atomicAdd(&cur[d], 1);
            srt[pos] = (int)(p & 0xFFFFu);
        }
        __syncthreads();
#pragma unroll
        for (int i = 0; i < 8; ++i) {
            int nd = wid * 8 + i;
            int s = boff_s[nd], epd = boff_s[nd + 1];
            dg[i] += epd - s;
            int e = s;
            for (; e + 3 < epd; e += 4) {
                int s0 = srt[e], s1 = srt[e + 1], s2 = srt[e + 2], s3 = srt[e + 3];
                unsigned int v0 = xu[(size_t)s0 * 64 + lane];
                unsigned int v1 = xu[(size_t)s1 * 64 + lane];
                unsigned int v2 = xu[(size_t)s2 * 64 + lane];
                unsigned int v3 = xu[(size_t)s3 * 64 + lane];
                ax[i] += (bf16lo_to_f32(v0) + bf16lo_to_f32(v1)) + (bf16lo_to_f32(v2) + bf16lo_to_f32(v3));
                ay[i] += (bf16hi_to_f32(v0) + bf16hi_to_f32(v1)) + (bf16hi_to_f32(v2) + bf16hi_to_f32(v3));
            }
            for (; e < epd; ++e) {
                unsigned int v0 = xu[(size_t)srt[e] * 64 + lane];
                ax[i] += bf16lo_to_f32(v0);
                ay[i] += bf16hi_to_f32(v0);
            }
        }
        __syncthreads();   // before next chunk overwrites raw/srt
    }

    int gbase = b0 * BUCK;
#pragma unroll
    for (int i = 0; i < 8; ++i) {
        int gnode = gbase + wid * 8 + i;
        if (gnode >= n) continue;
        float inv = (dg[i] > 0) ? 1.0f / (float)dg[i] : 0.f;
        float lo = ax[i] * inv, hi = ay[i] * inv;
        if (MEANBF) {
            unsigned int pk = (unsigned int)f32_to_bf16(lo) | ((unsigned int)f32_to_bf16(hi) << 16);
            reinterpret_cast<unsigned int*>(meanb)[(size_t)gnode * 64 + lane] = pk;
        } else {
            reinterpret_cast<float2*>(meanf + (size_t)gnode * DIM)[lane] = make_float2(lo, hi);
        }
    }
}

// Prep: pack W_B into bf16 MFMA B-fragment order + combined bias.
__global__ void prep_kernel(const float* __restrict__ w_self, const float* __restrict__ b_self,
                            const float* __restrict__ w_neigh, const float* __restrict__ b_neigh,
                            unsigned short* __restrict__ w_swz, float* __restrict__ bias) {
    int g = blockIdx.x * blockDim.x + threadIdx.x;
    if (g < 128) bias[g] = b_self[g] + b_neigh[g];
    if (g >= 64 * 64) return;
    int f = g >> 6, l = g & 63;
    int ks = f >> 3, nf = f & 7;
    int j = nf * 16 + (l & 15);
    int kbase = ks * 32 + ((l >> 4) << 3);
#pragma unroll
    for (int e = 0; e < 8; ++e) {
        int k = kbase + e;
        float v = (k < 128) ? w_self[(size_t)j * 128 + k] : w_neigh[(size_t)j * 128 + (k - 128)];
        w_swz[((size_t)g << 3) + e] = f32_to_bf16(v);
    }
}

// MFMA finalize: out = [x|mean]_bf16 @ W_B + bias.
#define FROWS 64
template <int MEANBF>
__global__ void finalize_kernel(const unsigned short* __restrict__ xb,
                                const float* __restrict__ meanf,
                                const unsigned short* __restrict__ meanb,
                                const unsigned short* __restrict__ w_swz,
                                const float* __restrict__ bias,
                                float* __restrict__ out, int n) {
    __shared__ unsigned short xm[FROWS][264];   // stride 132 dw -> 2-way max (free)
    int t = threadIdx.x;
    int base = blockIdx.x * FROWS;

    if (MEANBF) {
        for (int fi = t; fi < FROWS * 32; fi += NT) {
            int row = fi >> 5, c = fi & 31;
            int grow = base + row;
            ushort8 s = (ushort8)0;
            if (grow < n) {
                s = (c < 16)
                  ? reinterpret_cast<const ushort8*>(xb + (size_t)grow * DIM)[c]
                  : reinterpret_cast<const ushort8*>(meanb + (size_t)grow * DIM)[c - 16];
            }
            *reinterpret_cast<ushort8*>(&xm[row][c * 8]) = s;
        }
    } else {
        for (int fi = t; fi < FROWS * 16; fi += NT) {
            int row = fi >> 4, c = fi & 15;
            int grow = base + row;
            ushort8 s = (ushort8)0;
            if (grow < n) s = reinterpret_cast<const ushort8*>(xb + (size_t)grow * DIM)[c];
            *reinterpret_cast<ushort8*>(&xm[row][c * 8]) = s;
        }
        for (int fi = t; fi < FROWS * 32; fi += NT) {
            int row = fi >> 5, c4 = fi & 31;
            int grow = base + row;
            ushort4 sm = {0, 0, 0, 0};
            if (grow < n) {
                float4 mv = reinterpret_cast<const float4*>(meanf + (size_t)grow * DIM)[c4];
                sm = make_ushort4(f32_to_bf16(mv.x), f32_to_bf16(mv.y), f32_to_bf16(mv.z), f32_to_bf16(mv.w));
            }
            *reinterpret_cast<ushort4*>(&xm[row][128 + c4 * 4]) = sm;
        }
    }
    __syncthreads();

    int wave = t >> 6, lane = t & 63;
    int wrow = wave * 16;
    int arow = wrow + (lane & 15);
    int koff = (lane >> 4) << 3;

    f32x4 acc[8];
#pragma unroll
    for (int nf = 0; nf < 8; ++nf) acc[nf] = (f32x4){0.f, 0.f, 0.f, 0.f};

#pragma unroll
    for (int ks = 0; ks < 8; ++ks) {
        short8 a = *reinterpret_cast<const short8*>(&xm[arow][ks * 32 + koff]);
#pragma unroll
        for (int nf = 0; nf < 8; ++nf) {
            short8 b = *reinterpret_cast<const short8*>(
                w_swz + ((((size_t)ks * 8 + nf) * 64 + lane) << 3));
            acc[nf] = __builtin_amdgcn_mfma_f32_16x16x32_bf16(a, b, acc[nf], 0, 0, 0);
        }
    }

    int crow0 = wrow + ((lane >> 4) << 2);
#pragma unroll
    for (int nf = 0; nf < 8; ++nf) {
        int col = nf * 16 + (lane & 15);
        float bs = bias[col];
#pragma unroll
        for (int r = 0; r < 4; ++r) {
            int grow = base + crow0 + r;
            if (grow < n) out[(size_t)grow * DIM + col] = acc[nf][r] + bs;
        }
    }
}

extern "C" void kernel_launch(void* const* d_in, const int* in_sizes, int n_in,
                              void* d_out, int out_size, void* d_ws, size_t ws_size,
                              hipStream_t stream) {
    const float* x       = (const float*)d_in[0];
    const int*   ei      = (const int*)d_in[1];
    const float* w_self  = (const float*)d_in[2];
    const float* b_self  = (const float*)d_in[3];
    const float* w_neigh = (const float*)d_in[4];
    const float* b_neigh = (const float*)d_in[5];
    float* out = (float*)d_out;

    int n = in_sizes[0] / DIM;
    int E = in_sizes[1] / 2;
    int NB = (n + BUCK - 1) / BUCK;   // 782 for n=50000; requires NB <= NBMAX

    // ws: bcnt[NBMAX] | boffs[NBMAX+1] | bcursor[NBMAX] | csr uint[E] |
    //     (align16) w_swz bf16[32768] | bias f32[128] | x_bf bf16[n*128] | mean_bf bf16[n*128]
    int* bcnt    = (int*)d_ws;
    int* boffs   = bcnt + NBMAX;
    int* bcursor = boffs + NBMAX + 1;
    unsigned int* csr = (unsigned int*)(bcursor + NBMAX);
    unsigned short* w_swz = (unsigned short*)(((uintptr_t)(csr + E) + 15) & ~(uintptr_t)15);
    float* bias = (float*)(w_swz + 64 * 64 * 8);
    unsigned short* x_bf = (unsigned short*)(bias + 128);
    unsigned short* mean_bf = x_bf + (size_t)n * DIM;
    size_t need_full = (size_t)((char*)(mean_bf + (size_t)n * DIM) - (char*)d_ws);
    bool meanbf = ws_size >= need_full;

    hipMemsetAsync(bcnt, 0, (size_t)NB * sizeof(int), stream);

    prep_kernel<<<16, 256, 0, stream>>>(w_self, b_self, w_neigh, b_neigh, w_swz, bias);
    int n4 = n * DIM / 4;
    prepx_kernel<<<(n4 + NT - 1) / NT, NT, 0, stream>>>(x, x_bf, n4);

    int hblocks = (E + 4096 - 1) / 4096;
    bhist_kernel<<<hblocks, NT, 0, stream>>>(ei, bcnt, E, NB);
    bscan_kernel<<<1, NBMAX, 0, stream>>>(bcnt, boffs, bcursor, NB, E);
    int pblocks = (E + PCH - 1) / PCH;
    partition_kernel<<<pblocks, NT, 0, stream>>>(ei, bcursor, csr, E, NB);

    int fblocks = (n + FROWS - 1) / FROWS;
    if (meanbf) {
        bucket_aggregate_kernel<1><<<NB, BAT, 0, stream>>>(x_bf, boffs, csr, nullptr, mean_bf, n);
        finalize_kernel<1><<<fblocks, NT, 0, stream>>>(x_bf, nullptr, mean_bf, w_swz, bias, out, n);
    } else {
        bucket_aggregate_kernel<0><<<NB, BAT, 0, stream>>>(x_bf, boffs, csr, out, nullptr, n);
        finalize_kernel<0><<<fblocks, NT, 0, stream>>>(x_bf, out, nullptr, w_swz, bias, out, n);
    }
}

// Round 8
// 123.888 us; speedup vs baseline: 6.1535x; 1.0886x over previous
//
#include <hip/hip_runtime.h>

#define DIM 128
#define NT 256
#define BUCK 64          // dst nodes per bucket == MFMA tile rows
#define PCH 8192         // edges per partition chunk
#define NBMAX 1024       // max buckets supported (n <= 65536)
#define BAT 512          // threads in fused aggregate (8 waves x 8 nodes)
#define CAP 2048         // edges per aggregate sort chunk

typedef __attribute__((ext_vector_type(8))) short short8;
typedef __attribute__((ext_vector_type(8))) unsigned short ushort8;
typedef __attribute__((ext_vector_type(4))) float f32x4;

static __device__ __forceinline__ unsigned short f32_to_bf16(float f) {
    union { float f; unsigned int u; } c; c.f = f;
    unsigned int u = c.u;
    u += 0x7FFFu + ((u >> 16) & 1u);   // RNE
    return (unsigned short)(u >> 16);
}
static __device__ __forceinline__ float bf16lo_to_f32(unsigned int v) {
    union { unsigned int u; float f; } c; c.u = v << 16; return c.f;
}
static __device__ __forceinline__ float bf16hi_to_f32(unsigned int v) {
    union { unsigned int u; float f; } c; c.u = v & 0xFFFF0000u; return c.f;
}

// x (f32) -> x_bf (bf16), float4 per thread.
__global__ void prepx_kernel(const float* __restrict__ x, unsigned short* __restrict__ xb, int n4) {
    int g = blockIdx.x * blockDim.x + threadIdx.x;
    if (g >= n4) return;
    float4 v = reinterpret_cast<const float4*>(x)[g];
    ushort4 s = make_ushort4(f32_to_bf16(v.x), f32_to_bf16(v.y), f32_to_bf16(v.z), f32_to_bf16(v.w));
    reinterpret_cast<ushort4*>(xb)[g] = s;
}

// Bucket histogram, LDS-staged.
__global__ void bhist_kernel(const int* __restrict__ ei, int* __restrict__ bcnt, int E, int NB) {
    __shared__ int h[NBMAX];
    for (int i = threadIdx.x; i < NB; i += blockDim.x) h[i] = 0;
    __syncthreads();
    for (int e = blockIdx.x * blockDim.x + threadIdx.x; e < E; e += gridDim.x * blockDim.x)
        atomicAdd(&h[ei[E + e] >> 6], 1);
    __syncthreads();
    for (int i = threadIdx.x; i < NB; i += blockDim.x)
        if (h[i]) atomicAdd(&bcnt[i], h[i]);
}

// Single-block scan over NB (<=1024) buckets.
__global__ void bscan_kernel(const int* __restrict__ bcnt, int* __restrict__ boffs,
                             int* __restrict__ bcursor, int NB, int E) {
    __shared__ int sh[NBMAX];
    int t = threadIdx.x;
    int v = (t < NB) ? bcnt[t] : 0;
    sh[t] = v;
    __syncthreads();
    for (int d = 1; d < NBMAX; d <<= 1) {
        int u = (t >= d) ? sh[t - d] : 0;
        __syncthreads();
        sh[t] += u;
        __syncthreads();
    }
    if (t < NB) { int o = sh[t] - v; boffs[t] = o; bcursor[t] = o; }
    if (t == 0) boffs[NB] = E;
}

// Chunk-local partition: LDS histogram -> one cursor reservation per bucket ->
// scatter packed (dst<<16 | src) in contiguous per-bucket runs.
__global__ void partition_kernel(const int* __restrict__ ei, int* __restrict__ bcursor,
                                 unsigned int* __restrict__ csr, int E, int NB) {
    __shared__ int hist[NBMAX];
    __shared__ int wbase[NBMAX];
    __shared__ int lcur[NBMAX];
    int t = threadIdx.x;
    int cbase = blockIdx.x * PCH;
    int cend = min(E, cbase + PCH);
    for (int i = t; i < NB; i += NT) { hist[i] = 0; lcur[i] = 0; }
    __syncthreads();
    for (int e = cbase + t; e < cend; e += NT)
        atomicAdd(&hist[ei[E + e] >> 6], 1);
    __syncthreads();
    for (int b = t; b < NB; b += NT) {
        int c = hist[b];
        wbase[b] = c ? atomicAdd(&bcursor[b], c) : 0;
    }
    __syncthreads();
    for (int e = cbase + t; e < cend; e += NT) {
        unsigned int src = (unsigned int)ei[e];
        unsigned int dst = (unsigned int)ei[E + e];
        int b = (int)(dst >> 6);
        int r = atomicAdd(&lcur[b], 1);
        csr[wbase[b] + r] = (dst << 16) | src;
    }
}

// FUSED aggregate + finalize. One block per bucket (= 64 output rows).
// Phase 1: per 2048-edge chunk, LDS counting-sort by local dst, then wave w
//          accumulates nodes 8w..8w+7 in registers (float2/lane, 4 gathers deep).
// Phase 2: stage [x | mean]_bf16 into the 64x264 LDS tile (sort buffers reused),
//          8-wave MFMA (wave = 16-row x 64-col quadrant), write out + bias.
__global__ void __launch_bounds__(BAT)
fused_aggregate_kernel(const unsigned short* __restrict__ xb,
                       const int* __restrict__ boffs,
                       const unsigned int* __restrict__ csr,
                       const unsigned short* __restrict__ w_swz,
                       const float* __restrict__ bias,
                       float* __restrict__ out, int n) {
    __shared__ union {
        unsigned int rawsrt[2 * CAP];          // phase 1: raw | srt
        unsigned short xm[BUCK][264];          // phase 2: MFMA A-tile (stride 132 dw)
    } sh;
    __shared__ int bin[BUCK];
    __shared__ int boff_s[BUCK + 1];
    __shared__ int cur[BUCK];

    int tid = threadIdx.x, wid = tid >> 6, lane = tid & 63;
    int b0 = blockIdx.x;
    int start = boffs[b0], end = boffs[b0 + 1];
    const unsigned int* xu = reinterpret_cast<const unsigned int*>(xb);
    unsigned int* raw = sh.rawsrt;
    int* srt = (int*)(sh.rawsrt + CAP);

    float ax[8], ay[8];
    int dg[8];
#pragma unroll
    for (int i = 0; i < 8; ++i) { ax[i] = 0.f; ay[i] = 0.f; dg[i] = 0; }

    for (int cb = start; cb < end; cb += CAP) {
        int cnt = min(CAP, end - cb);
        for (int i = tid; i < cnt; i += BAT) raw[i] = csr[cb + i];
        for (int i = tid; i < BUCK; i += BAT) bin[i] = 0;
        __syncthreads();
        for (int i = tid; i < cnt; i += BAT) atomicAdd(&bin[(raw[i] >> 16) & 63], 1);
        __syncthreads();
        if (wid == 0) {   // wave-0 shuffle scan of 64 bins
            int v = bin[lane];
            int s = v;
            for (int d = 1; d < 64; d <<= 1) {
                int u = __shfl_up(s, d, 64);
                if (lane >= d) s += u;
            }
            boff_s[lane] = s - v;
            cur[lane] = s - v;
            if (lane == 63) boff_s[64] = s;
        }
        __syncthreads();
        for (int i = tid; i < cnt; i += BAT) {
            unsigned int p = raw[i];
            int d = (p >> 16) & 63;
            int pos = atomicAdd(&cur[d], 1);
            srt[pos] = (int)(p & 0xFFFFu);
        }
        __syncthreads();
#pragma unroll
        for (int i = 0; i < 8; ++i) {
            int nd = wid * 8 + i;
            int s = boff_s[nd], epd = boff_s[nd + 1];
            dg[i] += epd - s;
            int e = s;
            for (; e + 3 < epd; e += 4) {
                int s0 = srt[e], s1 = srt[e + 1], s2 = srt[e + 2], s3 = srt[e + 3];
                unsigned int v0 = xu[(size_t)s0 * 64 + lane];
                unsigned int v1 = xu[(size_t)s1 * 64 + lane];
                unsigned int v2 = xu[(size_t)s2 * 64 + lane];
                unsigned int v3 = xu[(size_t)s3 * 64 + lane];
                ax[i] += (bf16lo_to_f32(v0) + bf16lo_to_f32(v1)) + (bf16lo_to_f32(v2) + bf16lo_to_f32(v3));
                ay[i] += (bf16hi_to_f32(v0) + bf16hi_to_f32(v1)) + (bf16hi_to_f32(v2) + bf16hi_to_f32(v3));
            }
            for (; e < epd; ++e) {
                unsigned int v0 = xu[(size_t)srt[e] * 64 + lane];
                ax[i] += bf16lo_to_f32(v0);
                ay[i] += bf16hi_to_f32(v0);
            }
        }
        __syncthreads();   // raw/srt dead after this
    }

    // ---- Phase 2: build A-tile [x | mean] in LDS ----
    int gbase = b0 * BUCK;
    // x rows: 64 rows x 16 ushort8 chunks, coalesced.
    for (int fi = tid; fi < BUCK * 16; fi += BAT) {
        int row = fi >> 4, c = fi & 15;
        int grow = gbase + row;
        ushort8 s = (ushort8)0;
        if (grow < n) s = reinterpret_cast<const ushort8*>(xb + (size_t)grow * DIM)[c];
        *reinterpret_cast<ushort8*>(&sh.xm[row][c * 8]) = s;
    }
    // mean rows from registers: wave w owns rows 8w..8w+7; lane -> column pair.
#pragma unroll
    for (int i = 0; i < 8; ++i) {
        float inv = (dg[i] > 0) ? 1.0f / (float)dg[i] : 0.f;
        unsigned int pk = (unsigned int)f32_to_bf16(ax[i] * inv)
                        | ((unsigned int)f32_to_bf16(ay[i] * inv) << 16);
        *reinterpret_cast<unsigned int*>(&sh.xm[wid * 8 + i][128 + 2 * lane]) = pk;
    }
    __syncthreads();

    // ---- MFMA epilogue: wave = 16-row x 64-col quadrant ----
    int rg = wid >> 1, ch = wid & 1;
    int arow = rg * 16 + (lane & 15);
    int koff = (lane >> 4) << 3;

    f32x4 acc[4];
#pragma unroll
    for (int nf = 0; nf < 4; ++nf) acc[nf] = (f32x4){0.f, 0.f, 0.f, 0.f};

#pragma unroll
    for (int ks = 0; ks < 8; ++ks) {
        short8 a = *reinterpret_cast<const short8*>(&sh.xm[arow][ks * 32 + koff]);
#pragma unroll
        for (int nf = 0; nf < 4; ++nf) {
            int f = ks * 8 + ch * 4 + nf;
            short8 b = *reinterpret_cast<const short8*>(w_swz + (((size_t)f * 64 + lane) << 3));
            acc[nf] = __builtin_amdgcn_mfma_f32_16x16x32_bf16(a, b, acc[nf], 0, 0, 0);
        }
    }

    int crow0 = rg * 16 + ((lane >> 4) << 2);
#pragma unroll
    for (int nf = 0; nf < 4; ++nf) {
        int col = (ch * 4 + nf) * 16 + (lane & 15);
        float bs = bias[col];
#pragma unroll
        for (int r = 0; r < 4; ++r) {
            int grow = gbase + crow0 + r;
            if (grow < n) out[(size_t)grow * DIM + col] = acc[nf][r] + bs;
        }
    }
}

// Prep: pack W_B into bf16 MFMA B-fragment order + combined bias.
__global__ void prep_kernel(const float* __restrict__ w_self, const float* __restrict__ b_self,
                            const float* __restrict__ w_neigh, const float* __restrict__ b_neigh,
                            unsigned short* __restrict__ w_swz, float* __restrict__ bias) {
    int g = blockIdx.x * blockDim.x + threadIdx.x;
    if (g < 128) bias[g] = b_self[g] + b_neigh[g];
    if (g >= 64 * 64) return;
    int f = g >> 6, l = g & 63;
    int ks = f >> 3, nf = f & 7;
    int j = nf * 16 + (l & 15);
    int kbase = ks * 32 + ((l >> 4) << 3);
#pragma unroll
    for (int e = 0; e < 8; ++e) {
        int k = kbase + e;
        float v = (k < 128) ? w_self[(size_t)j * 128 + k] : w_neigh[(size_t)j * 128 + (k - 128)];
        w_swz[((size_t)g << 3) + e] = f32_to_bf16(v);
    }
}

extern "C" void kernel_launch(void* const* d_in, const int* in_sizes, int n_in,
                              void* d_out, int out_size, void* d_ws, size_t ws_size,
                              hipStream_t stream) {
    const float* x       = (const float*)d_in[0];
    const int*   ei      = (const int*)d_in[1];
    const float* w_self  = (const float*)d_in[2];
    const float* b_self  = (const float*)d_in[3];
    const float* w_neigh = (const float*)d_in[4];
    const float* b_neigh = (const float*)d_in[5];
    float* out = (float*)d_out;

    int n = in_sizes[0] / DIM;
    int E = in_sizes[1] / 2;
    int NB = (n + BUCK - 1) / BUCK;   // 782 for n=50000; requires NB <= NBMAX

    // ws: bcnt[NBMAX] | boffs[NBMAX+1] | bcursor[NBMAX] | csr uint[E] |
    //     (align16) w_swz bf16[32768] | bias f32[128] | x_bf bf16[n*128]
    int* bcnt    = (int*)d_ws;
    int* boffs   = bcnt + NBMAX;
    int* bcursor = boffs + NBMAX + 1;
    unsigned int* csr = (unsigned int*)(bcursor + NBMAX);
    unsigned short* w_swz = (unsigned short*)(((uintptr_t)(csr + E) + 15) & ~(uintptr_t)15);
    float* bias = (float*)(w_swz + 64 * 64 * 8);
    unsigned short* x_bf = (unsigned short*)(bias + 128);

    hipMemsetAsync(bcnt, 0, (size_t)NB * sizeof(int), stream);

    prep_kernel<<<16, 256, 0, stream>>>(w_self, b_self, w_neigh, b_neigh, w_swz, bias);
    int n4 = n * DIM / 4;
    prepx_kernel<<<(n4 + NT - 1) / NT, NT, 0, stream>>>(x, x_bf, n4);

    int hblocks = (E + 4096 - 1) / 4096;
    bhist_kernel<<<hblocks, NT, 0, stream>>>(ei, bcnt, E, NB);
    bscan_kernel<<<1, NBMAX, 0, stream>>>(bcnt, boffs, bcursor, NB, E);
    int pblocks = (E + PCH - 1) / PCH;
    partition_kernel<<<pblocks, NT, 0, stream>>>(ei, bcursor, csr, E, NB);

    fused_aggregate_kernel<<<NB, BAT, 0, stream>>>(x_bf, boffs, csr, w_swz, bias, out, n);
}

// Round 9
// 109.850 us; speedup vs baseline: 6.9398x; 1.1278x over previous
//
#include <hip/hip_runtime.h>

#define DIM 128
#define NT 256
#define BUCK 64          // dst nodes per bucket == MFMA tile rows
#define PCH 8192         // edges per partition chunk
#define NBMAX 1024       // max buckets supported (n <= 65536)
#define BAT 512          // threads in fused aggregate (8 waves x 8 nodes)
#define CAP 2048         // edges per aggregate sort chunk
#define PREPX_BLKS 1024
#define HIST_BLKS 196
#define PREP_BLKS 16

typedef __attribute__((ext_vector_type(8))) short short8;
typedef __attribute__((ext_vector_type(8))) unsigned short ushort8;
typedef __attribute__((ext_vector_type(4))) float f32x4;

static __device__ __forceinline__ unsigned short f32_to_bf16(float f) {
    union { float f; unsigned int u; } c; c.f = f;
    unsigned int u = c.u;
    u += 0x7FFFu + ((u >> 16) & 1u);   // RNE
    return (unsigned short)(u >> 16);
}
static __device__ __forceinline__ float bf16lo_to_f32(unsigned int v) {
    union { unsigned int u; float f; } c; c.u = v << 16; return c.f;
}
static __device__ __forceinline__ float bf16hi_to_f32(unsigned int v) {
    union { unsigned int u; float f; } c; c.u = v & 0xFFFF0000u; return c.f;
}

// Fused setup: blocks [0,PREPX) convert x->bf16; [PREPX,PREPX+HIST) bucket-histogram;
// [.., +PREP) pack weights + bias. All independent.
__global__ void setup_kernel(const float* __restrict__ x, const int* __restrict__ ei,
                             const float* __restrict__ w_self, const float* __restrict__ b_self,
                             const float* __restrict__ w_neigh, const float* __restrict__ b_neigh,
                             unsigned short* __restrict__ xb, unsigned short* __restrict__ w_swz,
                             float* __restrict__ bias, int* __restrict__ bcnt,
                             int n4, int E, int NB) {
    int b = blockIdx.x, t = threadIdx.x;
    if (b < PREPX_BLKS) {
        for (int g = b * NT + t; g < n4; g += PREPX_BLKS * NT) {
            float4 v = reinterpret_cast<const float4*>(x)[g];
            ushort4 s = make_ushort4(f32_to_bf16(v.x), f32_to_bf16(v.y),
                                     f32_to_bf16(v.z), f32_to_bf16(v.w));
            reinterpret_cast<ushort4*>(xb)[g] = s;
        }
    } else if (b < PREPX_BLKS + HIST_BLKS) {
        __shared__ int h[NBMAX];
        for (int i = t; i < NB; i += NT) h[i] = 0;
        __syncthreads();
        int bb = b - PREPX_BLKS;
        for (int e = bb * NT + t; e < E; e += HIST_BLKS * NT)
            atomicAdd(&h[ei[E + e] >> 6], 1);
        __syncthreads();
        for (int i = t; i < NB; i += NT)
            if (h[i]) atomicAdd(&bcnt[i], h[i]);
    } else {
        int g = (b - PREPX_BLKS - HIST_BLKS) * NT + t;   // 4096 slots
        if (g < 128) bias[g] = b_self[g] + b_neigh[g];
        if (g >= 64 * 64) return;
        int f = g >> 6, l = g & 63;
        int ks = f >> 3, nf = f & 7;
        int j = nf * 16 + (l & 15);
        int kbase = ks * 32 + ((l >> 4) << 3);
#pragma unroll
        for (int e = 0; e < 8; ++e) {
            int k = kbase + e;
            float v = (k < 128) ? w_self[(size_t)j * 128 + k]
                                : w_neigh[(size_t)j * 128 + (k - 128)];
            w_swz[((size_t)g << 3) + e] = f32_to_bf16(v);
        }
    }
}

// Single-block scan over NB (<=1024) buckets.
__global__ void bscan_kernel(const int* __restrict__ bcnt, int* __restrict__ boffs,
                             int* __restrict__ bcursor, int NB, int E) {
    __shared__ int sh[NBMAX];
    int t = threadIdx.x;
    int v = (t < NB) ? bcnt[t] : 0;
    sh[t] = v;
    __syncthreads();
    for (int d = 1; d < NBMAX; d <<= 1) {
        int u = (t >= d) ? sh[t - d] : 0;
        __syncthreads();
        sh[t] += u;
        __syncthreads();
    }
    if (t < NB) { int o = sh[t] - v; boffs[t] = o; bcursor[t] = o; }
    if (t == 0) boffs[NB] = E;
}

// Chunk-local partition: LDS histogram -> one cursor reservation per bucket ->
// scatter packed (dst<<16 | src) in contiguous per-bucket runs.
__global__ void partition_kernel(const int* __restrict__ ei, int* __restrict__ bcursor,
                                 unsigned int* __restrict__ csr, int E, int NB) {
    __shared__ int hist[NBMAX];
    __shared__ int wbase[NBMAX];
    __shared__ int lcur[NBMAX];
    int t = threadIdx.x;
    int cbase = blockIdx.x * PCH;
    int cend = min(E, cbase + PCH);
    for (int i = t; i < NB; i += NT) { hist[i] = 0; lcur[i] = 0; }
    __syncthreads();
    for (int e = cbase + t; e < cend; e += NT)
        atomicAdd(&hist[ei[E + e] >> 6], 1);
    __syncthreads();
    for (int b = t; b < NB; b += NT) {
        int c = hist[b];
        wbase[b] = c ? atomicAdd(&bcursor[b], c) : 0;
    }
    __syncthreads();
    for (int e = cbase + t; e < cend; e += NT) {
        unsigned int src = (unsigned int)ei[e];
        unsigned int dst = (unsigned int)ei[E + e];
        int b = (int)(dst >> 6);
        int r = atomicAdd(&lcur[b], 1);
        csr[wbase[b] + r] = (dst << 16) | src;
    }
}

// FUSED aggregate + finalize. One block per bucket (= 64 output rows).
// Phase 1: LDS counting-sort by local dst, then wave w accumulates nodes
//          8w..8w+7 in registers, 8 gathers in flight.
// Phase 2: stage [x | mean]_bf16 into 64x264 LDS tile, 8-wave MFMA, write out.
__global__ void __launch_bounds__(BAT)
fused_aggregate_kernel(const unsigned short* __restrict__ xb,
                       const int* __restrict__ boffs,
                       const unsigned int* __restrict__ csr,
                       const unsigned short* __restrict__ w_swz,
                       const float* __restrict__ bias,
                       float* __restrict__ out, int n) {
    __shared__ union {
        unsigned int rawsrt[2 * CAP];          // phase 1: raw | srt
        unsigned short xm[BUCK][264];          // phase 2: MFMA A-tile (stride 132 dw)
    } sh;
    __shared__ int bin[BUCK];
    __shared__ int boff_s[BUCK + 1];
    __shared__ int cur[BUCK];

    int tid = threadIdx.x, wid = tid >> 6, lane = tid & 63;
    int b0 = blockIdx.x;
    int start = boffs[b0], end = boffs[b0 + 1];
    const unsigned int* xu = reinterpret_cast<const unsigned int*>(xb);
    unsigned int* raw = sh.rawsrt;
    int* srt = (int*)(sh.rawsrt + CAP);

    float ax[8], ay[8];
    int dg[8];
#pragma unroll
    for (int i = 0; i < 8; ++i) { ax[i] = 0.f; ay[i] = 0.f; dg[i] = 0; }

    for (int cb = start; cb < end; cb += CAP) {
        int cnt = min(CAP, end - cb);
        for (int i = tid; i < cnt; i += BAT) raw[i] = csr[cb + i];
        for (int i = tid; i < BUCK; i += BAT) bin[i] = 0;
        __syncthreads();
        for (int i = tid; i < cnt; i += BAT) atomicAdd(&bin[(raw[i] >> 16) & 63], 1);
        __syncthreads();
        if (wid == 0) {   // wave-0 shuffle scan of 64 bins
            int v = bin[lane];
            int s = v;
            for (int d = 1; d < 64; d <<= 1) {
                int u = __shfl_up(s, d, 64);
                if (lane >= d) s += u;
            }
            boff_s[lane] = s - v;
            cur[lane] = s - v;
            if (lane == 63) boff_s[64] = s;
        }
        __syncthreads();
        for (int i = tid; i < cnt; i += BAT) {
            unsigned int p = raw[i];
            int d = (p >> 16) & 63;
            int pos = atomicAdd(&cur[d], 1);
            srt[pos] = (int)(p & 0xFFFFu);
        }
        __syncthreads();
#pragma unroll
        for (int i = 0; i < 8; ++i) {
            int nd = wid * 8 + i;
            int s = boff_s[nd], epd = boff_s[nd + 1];
            dg[i] += epd - s;
            int e = s;
            for (; e + 7 < epd; e += 8) {   // 8 gathers in flight
                unsigned int v0 = xu[(size_t)srt[e]     * 64 + lane];
                unsigned int v1 = xu[(size_t)srt[e + 1] * 64 + lane];
                unsigned int v2 = xu[(size_t)srt[e + 2] * 64 + lane];
                unsigned int v3 = xu[(size_t)srt[e + 3] * 64 + lane];
                unsigned int v4 = xu[(size_t)srt[e + 4] * 64 + lane];
                unsigned int v5 = xu[(size_t)srt[e + 5] * 64 + lane];
                unsigned int v6 = xu[(size_t)srt[e + 6] * 64 + lane];
                unsigned int v7 = xu[(size_t)srt[e + 7] * 64 + lane];
                ax[i] += ((bf16lo_to_f32(v0) + bf16lo_to_f32(v1)) + (bf16lo_to_f32(v2) + bf16lo_to_f32(v3)))
                       + ((bf16lo_to_f32(v4) + bf16lo_to_f32(v5)) + (bf16lo_to_f32(v6) + bf16lo_to_f32(v7)));
                ay[i] += ((bf16hi_to_f32(v0) + bf16hi_to_f32(v1)) + (bf16hi_to_f32(v2) + bf16hi_to_f32(v3)))
                       + ((bf16hi_to_f32(v4) + bf16hi_to_f32(v5)) + (bf16hi_to_f32(v6) + bf16hi_to_f32(v7)));
            }
            for (; e + 3 < epd; e += 4) {
                unsigned int v0 = xu[(size_t)srt[e]     * 64 + lane];
                unsigned int v1 = xu[(size_t)srt[e + 1] * 64 + lane];
                unsigned int v2 = xu[(size_t)srt[e + 2] * 64 + lane];
                unsigned int v3 = xu[(size_t)srt[e + 3] * 64 + lane];
                ax[i] += (bf16lo_to_f32(v0) + bf16lo_to_f32(v1)) + (bf16lo_to_f32(v2) + bf16lo_to_f32(v3));
                ay[i] += (bf16hi_to_f32(v0) + bf16hi_to_f32(v1)) + (bf16hi_to_f32(v2) + bf16hi_to_f32(v3));
            }
            for (; e < epd; ++e) {
                unsigned int v0 = xu[(size_t)srt[e] * 64 + lane];
                ax[i] += bf16lo_to_f32(v0);
                ay[i] += bf16hi_to_f32(v0);
            }
        }
        __syncthreads();   // raw/srt dead after this
    }

    // ---- Phase 2: build A-tile [x | mean] in LDS ----
    int gbase = b0 * BUCK;
    for (int fi = tid; fi < BUCK * 16; fi += BAT) {
        int row = fi >> 4, c = fi & 15;
        int grow = gbase + row;
        ushort8 s = (ushort8)0;
        if (grow < n) s = reinterpret_cast<const ushort8*>(xb + (size_t)grow * DIM)[c];
        *reinterpret_cast<ushort8*>(&sh.xm[row][c * 8]) = s;
    }
#pragma unroll
    for (int i = 0; i < 8; ++i) {
        float inv = (dg[i] > 0) ? 1.0f / (float)dg[i] : 0.f;
        unsigned int pk = (unsigned int)f32_to_bf16(ax[i] * inv)
                        | ((unsigned int)f32_to_bf16(ay[i] * inv) << 16);
        *reinterpret_cast<unsigned int*>(&sh.xm[wid * 8 + i][128 + 2 * lane]) = pk;
    }
    __syncthreads();

    // ---- MFMA epilogue: wave = 16-row x 64-col quadrant ----
    int rg = wid >> 1, ch = wid & 1;
    int arow = rg * 16 + (lane & 15);
    int koff = (lane >> 4) << 3;

    f32x4 acc[4];
#pragma unroll
    for (int nf = 0; nf < 4; ++nf) acc[nf] = (f32x4){0.f, 0.f, 0.f, 0.f};

#pragma unroll
    for (int ks = 0; ks < 8; ++ks) {
        short8 a = *reinterpret_cast<const short8*>(&sh.xm[arow][ks * 32 + koff]);
#pragma unroll
        for (int nf = 0; nf < 4; ++nf) {
            int f = ks * 8 + ch * 4 + nf;
            short8 b = *reinterpret_cast<const short8*>(w_swz + (((size_t)f * 64 + lane) << 3));
            acc[nf] = __builtin_amdgcn_mfma_f32_16x16x32_bf16(a, b, acc[nf], 0, 0, 0);
        }
    }

    int crow0 = rg * 16 + ((lane >> 4) << 2);
#pragma unroll
    for (int nf = 0; nf < 4; ++nf) {
        int col = (ch * 4 + nf) * 16 + (lane & 15);
        float bs = bias[col];
#pragma unroll
        for (int r = 0; r < 4; ++r) {
            int grow = gbase + crow0 + r;
            if (grow < n) out[(size_t)grow * DIM + col] = acc[nf][r] + bs;
        }
    }
}

extern "C" void kernel_launch(void* const* d_in, const int* in_sizes, int n_in,
                              void* d_out, int out_size, void* d_ws, size_t ws_size,
                              hipStream_t stream) {
    const float* x       = (const float*)d_in[0];
    const int*   ei      = (const int*)d_in[1];
    const float* w_self  = (const float*)d_in[2];
    const float* b_self  = (const float*)d_in[3];
    const float* w_neigh = (const float*)d_in[4];
    const float* b_neigh = (const float*)d_in[5];
    float* out = (float*)d_out;

    int n = in_sizes[0] / DIM;
    int E = in_sizes[1] / 2;
    int NB = (n + BUCK - 1) / BUCK;   // 782 for n=50000; requires NB <= NBMAX

    // ws: bcnt[NBMAX] | boffs[NBMAX+1] | bcursor[NBMAX] | csr uint[E] |
    //     (align16) w_swz bf16[32768] | bias f32[128] | x_bf bf16[n*128]
    int* bcnt    = (int*)d_ws;
    int* boffs   = bcnt + NBMAX;
    int* bcursor = boffs + NBMAX + 1;
    unsigned int* csr = (unsigned int*)(bcursor + NBMAX);
    unsigned short* w_swz = (unsigned short*)(((uintptr_t)(csr + E) + 15) & ~(uintptr_t)15);
    float* bias = (float*)(w_swz + 64 * 64 * 8);
    unsigned short* x_bf = (unsigned short*)(bias + 128);

    hipMemsetAsync(bcnt, 0, (size_t)NB * sizeof(int), stream);

    int n4 = n * DIM / 4;
    setup_kernel<<<PREPX_BLKS + HIST_BLKS + PREP_BLKS, NT, 0, stream>>>(
        x, ei, w_self, b_self, w_neigh, b_neigh, x_bf, w_swz, bias, bcnt, n4, E, NB);

    bscan_kernel<<<1, NBMAX, 0, stream>>>(bcnt, boffs, bcursor, NB, E);
    int pblocks = (E + PCH - 1) / PCH;
    partition_kernel<<<pblocks, NT, 0, stream>>>(ei, bcursor, csr, E, NB);

    fused_aggregate_kernel<<<NB, BAT, 0, stream>>>(x_bf, boffs, csr, w_swz, bias, out, n);
}

// Round 10
// 107.462 us; speedup vs baseline: 7.0941x; 1.0222x over previous
//
#include <hip/hip_runtime.h>

#define DIM 128
#define NT 256
#define BUCK 64          // dst nodes per bucket == MFMA tile rows
#define PCH 8192         // edges per partition chunk
#define NBMAX 1024       // max buckets supported (n <= 65536)
#define BAT 512          // threads in fused aggregate (8 waves x 8 nodes)
#define CAP 4096         // max edges per bucket for in-LDS sort (else fallback)
#define PREPX_BLKS 1024
#define HIST_BLKS 196
#define PREP_BLKS 16

typedef __attribute__((ext_vector_type(8))) short short8;
typedef __attribute__((ext_vector_type(8))) unsigned short ushort8;
typedef __attribute__((ext_vector_type(4))) float f32x4;

static __device__ __forceinline__ unsigned short f32_to_bf16(float f) {
    union { float f; unsigned int u; } c; c.f = f;
    unsigned int u = c.u;
    u += 0x7FFFu + ((u >> 16) & 1u);   // RNE
    return (unsigned short)(u >> 16);
}
static __device__ __forceinline__ float bf16lo_to_f32(unsigned int v) {
    union { unsigned int u; float f; } c; c.u = v << 16; return c.f;
}
static __device__ __forceinline__ float bf16hi_to_f32(unsigned int v) {
    union { unsigned int u; float f; } c; c.u = v & 0xFFFF0000u; return c.f;
}

// Fused setup: blocks [0,PREPX) convert x->bf16; [PREPX,PREPX+HIST) bucket-histogram;
// [.., +PREP) pack weights + bias. All independent.
__global__ void setup_kernel(const float* __restrict__ x, const int* __restrict__ ei,
                             const float* __restrict__ w_self, const float* __restrict__ b_self,
                             const float* __restrict__ w_neigh, const float* __restrict__ b_neigh,
                             unsigned short* __restrict__ xb, unsigned short* __restrict__ w_swz,
                             float* __restrict__ bias, int* __restrict__ bcnt,
                             int n4, int E, int NB) {
    int b = blockIdx.x, t = threadIdx.x;
    if (b < PREPX_BLKS) {
        for (int g = b * NT + t; g < n4; g += PREPX_BLKS * NT) {
            float4 v = reinterpret_cast<const float4*>(x)[g];
            ushort4 s = make_ushort4(f32_to_bf16(v.x), f32_to_bf16(v.y),
                                     f32_to_bf16(v.z), f32_to_bf16(v.w));
            reinterpret_cast<ushort4*>(xb)[g] = s;
        }
    } else if (b < PREPX_BLKS + HIST_BLKS) {
        __shared__ int h[NBMAX];
        for (int i = t; i < NB; i += NT) h[i] = 0;
        __syncthreads();
        int bb = b - PREPX_BLKS;
        for (int e = bb * NT + t; e < E; e += HIST_BLKS * NT)
            atomicAdd(&h[ei[E + e] >> 6], 1);
        __syncthreads();
        for (int i = t; i < NB; i += NT)
            if (h[i]) atomicAdd(&bcnt[i], h[i]);
    } else {
        int g = (b - PREPX_BLKS - HIST_BLKS) * NT + t;   // 4096 slots
        if (g < 128) bias[g] = b_self[g] + b_neigh[g];
        if (g >= 64 * 64) return;
        int f = g >> 6, l = g & 63;
        int ks = f >> 3, nf = f & 7;
        int j = nf * 16 + (l & 15);
        int kbase = ks * 32 + ((l >> 4) << 3);
#pragma unroll
        for (int e = 0; e < 8; ++e) {
            int k = kbase + e;
            float v = (k < 128) ? w_self[(size_t)j * 128 + k]
                                : w_neigh[(size_t)j * 128 + (k - 128)];
            w_swz[((size_t)g << 3) + e] = f32_to_bf16(v);
        }
    }
}

// Single-block scan over NB (<=1024) buckets.
__global__ void bscan_kernel(const int* __restrict__ bcnt, int* __restrict__ boffs,
                             int* __restrict__ bcursor, int NB, int E) {
    __shared__ int sh[NBMAX];
    int t = threadIdx.x;
    int v = (t < NB) ? bcnt[t] : 0;
    sh[t] = v;
    __syncthreads();
    for (int d = 1; d < NBMAX; d <<= 1) {
        int u = (t >= d) ? sh[t - d] : 0;
        __syncthreads();
        sh[t] += u;
        __syncthreads();
    }
    if (t < NB) { int o = sh[t] - v; boffs[t] = o; bcursor[t] = o; }
    if (t == 0) boffs[NB] = E;
}

// Chunk-local partition: LDS histogram -> one cursor reservation per bucket ->
// scatter packed (dst<<16 | src) in contiguous per-bucket runs.
__global__ void partition_kernel(const int* __restrict__ ei, int* __restrict__ bcursor,
                                 unsigned int* __restrict__ csr, int E, int NB) {
    __shared__ int hist[NBMAX];
    __shared__ int wbase[NBMAX];
    __shared__ int lcur[NBMAX];
    int t = threadIdx.x;
    int cbase = blockIdx.x * PCH;
    int cend = min(E, cbase + PCH);
    for (int i = t; i < NB; i += NT) { hist[i] = 0; lcur[i] = 0; }
    __syncthreads();
    for (int e = cbase + t; e < cend; e += NT)
        atomicAdd(&hist[ei[E + e] >> 6], 1);
    __syncthreads();
    for (int b = t; b < NB; b += NT) {
        int c = hist[b];
        wbase[b] = c ? atomicAdd(&bcursor[b], c) : 0;
    }
    __syncthreads();
    for (int e = cbase + t; e < cend; e += NT) {
        unsigned int src = (unsigned int)ei[e];
        unsigned int dst = (unsigned int)ei[E + e];
        int b = (int)(dst >> 6);
        int r = atomicAdd(&lcur[b], 1);
        csr[wbase[b] + r] = (dst << 16) | src;
    }
}

// FUSED aggregate + finalize. One block per bucket (= 64 output rows).
// Gather: ONE dwordx4 instruction fetches 4 edges (16 lanes x 16B per 256B row).
// Wave w owns nodes 8w..8w+7; per node, 16 edges (4 quad-loads) in flight;
// cross-lane-group reduce (2 shfl_xor) -> mean written into the MFMA A-tile.
__global__ void __launch_bounds__(BAT)
fused_aggregate_kernel(const unsigned short* __restrict__ xb,
                       const int* __restrict__ boffs,
                       const unsigned int* __restrict__ csr,
                       const unsigned short* __restrict__ w_swz,
                       const float* __restrict__ bias,
                       float* __restrict__ out, int n) {
    __shared__ int srt[CAP];
    __shared__ unsigned short xm[BUCK][264];   // [x(128) | mean(128)] bf16, stride 132 dw
    __shared__ int bin[BUCK];
    __shared__ int boff_s[BUCK + 1];
    __shared__ int cur[BUCK];

    int tid = threadIdx.x, wid = tid >> 6, lane = tid & 63;
    int grp = lane >> 4, j = lane & 15;     // 4 groups of 16 lanes
    int b0 = blockIdx.x;
    int start = boffs[b0], end = boffs[b0 + 1];
    int bsize = end - start;
    int gbase = b0 * BUCK;
    const uint4* x16 = reinterpret_cast<const uint4*>(xb);   // 16 uint4 per row

    // Stage x rows into A-tile x-part (coalesced; barriers below order vs MFMA).
    for (int fi = tid; fi < BUCK * 16; fi += BAT) {
        int row = fi >> 4, c = fi & 15;
        int grow = gbase + row;
        ushort8 s = (ushort8)0;
        if (grow < n) s = reinterpret_cast<const ushort8*>(xb + (size_t)grow * DIM)[c];
        *reinterpret_cast<ushort8*>(&xm[row][c * 8]) = s;
    }

    if (bsize <= CAP) {
        // ---- whole-bucket counting sort by local dst ----
        for (int i = tid; i < BUCK; i += BAT) bin[i] = 0;
        __syncthreads();
        for (int i = tid; i < bsize; i += BAT)
            atomicAdd(&bin[(csr[start + i] >> 16) & 63], 1);
        __syncthreads();
        if (wid == 0) {   // wave-0 shuffle scan of 64 bins
            int v = bin[lane];
            int s = v;
            for (int d = 1; d < 64; d <<= 1) {
                int u = __shfl_up(s, d, 64);
                if (lane >= d) s += u;
            }
            boff_s[lane] = s - v;
            cur[lane] = s - v;
            if (lane == 63) boff_s[64] = s;
        }
        __syncthreads();
        for (int i = tid; i < bsize; i += BAT) {
            unsigned int p = csr[start + i];
            int d = (p >> 16) & 63;
            srt[atomicAdd(&cur[d], 1)] = (int)(p & 0xFFFFu);
        }
        __syncthreads();

        // ---- per-node gather, 4 edges/instr, 16 edges in flight ----
#pragma unroll 2
        for (int i = 0; i < 8; ++i) {
            int nd = wid * 8 + i;
            int s = boff_s[nd], epd = boff_s[nd + 1];
            float acc[8];
#pragma unroll
            for (int k = 0; k < 8; ++k) acc[k] = 0.f;
            for (int e = s; e < epd; e += 16) {
                uint4 v[4];
#pragma unroll
                for (int q = 0; q < 4; ++q) {
                    int eidx = e + q * 4 + grp;
                    bool ok = eidx < epd;
                    int src = srt[ok ? eidx : s];
                    uint4 t = x16[(size_t)src * 16 + j];
                    if (!ok) t = (uint4){0u, 0u, 0u, 0u};
                    v[q] = t;
                }
#pragma unroll
                for (int q = 0; q < 4; ++q) {
                    acc[0] += bf16lo_to_f32(v[q].x); acc[1] += bf16hi_to_f32(v[q].x);
                    acc[2] += bf16lo_to_f32(v[q].y); acc[3] += bf16hi_to_f32(v[q].y);
                    acc[4] += bf16lo_to_f32(v[q].z); acc[5] += bf16hi_to_f32(v[q].z);
                    acc[6] += bf16lo_to_f32(v[q].w); acc[7] += bf16hi_to_f32(v[q].w);
                }
            }
            // cross-group reduce: sum the 4 lane-groups (same col set each).
#pragma unroll
            for (int k = 0; k < 8; ++k) {
                acc[k] += __shfl_xor(acc[k], 16);
                acc[k] += __shfl_xor(acc[k], 32);
            }
            int deg = epd - s;
            float inv = deg > 0 ? 1.0f / (float)deg : 0.f;
            if (grp == 0) {
                ushort8 m = (ushort8)0;
#pragma unroll
                for (int k = 0; k < 8; ++k) m[k] = f32_to_bf16(acc[k] * inv);
                *reinterpret_cast<ushort8*>(&xm[nd][128 + j * 8]) = m;
            }
        }
    } else {
        // Fallback (bucket > CAP — never on this input): per-node scan of csr.
        for (int i = 0; i < 8; ++i) {
            int nd = wid * 8 + i;
            float acc[8];
#pragma unroll
            for (int k = 0; k < 8; ++k) acc[k] = 0.f;
            int deg = 0;
            for (int e = start; e < end; ++e) {
                unsigned int p = csr[e];
                if ((int)((p >> 16) & 63u) != nd) continue;
                ++deg;
                uint4 v = x16[(size_t)(p & 0xFFFFu) * 16 + j];
                if (grp == 0) {
                    acc[0] += bf16lo_to_f32(v.x); acc[1] += bf16hi_to_f32(v.x);
                    acc[2] += bf16lo_to_f32(v.y); acc[3] += bf16hi_to_f32(v.y);
                    acc[4] += bf16lo_to_f32(v.z); acc[5] += bf16hi_to_f32(v.z);
                    acc[6] += bf16lo_to_f32(v.w); acc[7] += bf16hi_to_f32(v.w);
                }
            }
#pragma unroll
            for (int k = 0; k < 8; ++k) {
                acc[k] += __shfl_xor(acc[k], 16);
                acc[k] += __shfl_xor(acc[k], 32);
            }
            float inv = deg > 0 ? 1.0f / (float)deg : 0.f;
            if (grp == 0) {
                ushort8 m = (ushort8)0;
#pragma unroll
                for (int k = 0; k < 8; ++k) m[k] = f32_to_bf16(acc[k] * inv);
                *reinterpret_cast<ushort8*>(&xm[nd][128 + j * 8]) = m;
            }
        }
    }
    __syncthreads();

    // ---- MFMA epilogue: wave = 16-row x 64-col quadrant ----
    int rg = wid >> 1, ch = wid & 1;
    int arow = rg * 16 + (lane & 15);
    int koff = (lane >> 4) << 3;

    f32x4 acc[4];
#pragma unroll
    for (int nf = 0; nf < 4; ++nf) acc[nf] = (f32x4){0.f, 0.f, 0.f, 0.f};

#pragma unroll
    for (int ks = 0; ks < 8; ++ks) {
        short8 a = *reinterpret_cast<const short8*>(&xm[arow][ks * 32 + koff]);
#pragma unroll
        for (int nf = 0; nf < 4; ++nf) {
            int f = ks * 8 + ch * 4 + nf;
            short8 b = *reinterpret_cast<const short8*>(w_swz + (((size_t)f * 64 + lane) << 3));
            acc[nf] = __builtin_amdgcn_mfma_f32_16x16x32_bf16(a, b, acc[nf], 0, 0, 0);
        }
    }

    int crow0 = rg * 16 + ((lane >> 4) << 2);
#pragma unroll
    for (int nf = 0; nf < 4; ++nf) {
        int col = (ch * 4 + nf) * 16 + (lane & 15);
        float bs = bias[col];
#pragma unroll
        for (int r = 0; r < 4; ++r) {
            int grow = gbase + crow0 + r;
            if (grow < n) out[(size_t)grow * DIM + col] = acc[nf][r] + bs;
        }
    }
}

extern "C" void kernel_launch(void* const* d_in, const int* in_sizes, int n_in,
                              void* d_out, int out_size, void* d_ws, size_t ws_size,
                              hipStream_t stream) {
    const float* x       = (const float*)d_in[0];
    const int*   ei      = (const int*)d_in[1];
    const float* w_self  = (const float*)d_in[2];
    const float* b_self  = (const float*)d_in[3];
    const float* w_neigh = (const float*)d_in[4];
    const float* b_neigh = (const float*)d_in[5];
    float* out = (float*)d_out;

    int n = in_sizes[0] / DIM;
    int E = in_sizes[1] / 2;
    int NB = (n + BUCK - 1) / BUCK;   // 782 for n=50000; requires NB <= NBMAX

    // ws: bcnt[NBMAX] | boffs[NBMAX+1] | bcursor[NBMAX] | csr uint[E] |
    //     (align16) w_swz bf16[32768] | bias f32[128] | x_bf bf16[n*128]
    int* bcnt    = (int*)d_ws;
    int* boffs   = bcnt + NBMAX;
    int* bcursor = boffs + NBMAX + 1;
    unsigned int* csr = (unsigned int*)(bcursor + NBMAX);
    unsigned short* w_swz = (unsigned short*)(((uintptr_t)(csr + E) + 15) & ~(uintptr_t)15);
    float* bias = (float*)(w_swz + 64 * 64 * 8);
    unsigned short* x_bf = (unsigned short*)(bias + 128);

    hipMemsetAsync(bcnt, 0, (size_t)NB * sizeof(int), stream);

    int n4 = n * DIM / 4;
    setup_kernel<<<PREPX_BLKS + HIST_BLKS + PREP_BLKS, NT, 0, stream>>>(
        x, ei, w_self, b_self, w_neigh, b_neigh, x_bf, w_swz, bias, bcnt, n4, E, NB);

    bscan_kernel<<<1, NBMAX, 0, stream>>>(bcnt, boffs, bcursor, NB, E);
    int pblocks = (E + PCH - 1) / PCH;
    partition_kernel<<<pblocks, NT, 0, stream>>>(ei, bcursor, csr, E, NB);

    fused_aggregate_kernel<<<NB, BAT, 0, stream>>>(x_bf, boffs, csr, w_swz, bias, out, n);
}

// Round 11
// 86.167 us; speedup vs baseline: 8.8472x; 1.2471x over previous
//
#include <hip/hip_runtime.h>

#define DIM 128
#define NT 256
#define BUCK 64          // dst nodes per bucket == MFMA tile rows
#define PCH 8192         // edges per partition chunk
#define NBMAX 1024       // max buckets supported (n <= 65536)
#define BAT 512          // threads in fused aggregate (8 waves x 8 nodes)
#define CAPB 2048        // fixed csr slots per bucket (avg 1023, max ~1.2k; overflow-safe)
#define CONV_BLKS 512
#define WPACK_BLKS 16

typedef __attribute__((ext_vector_type(8))) short short8;
typedef __attribute__((ext_vector_type(8))) unsigned short ushort8;
typedef __attribute__((ext_vector_type(4))) float f32x4;

static __device__ __forceinline__ unsigned short f32_to_bf16(float f) {
    union { float f; unsigned int u; } c; c.f = f;
    unsigned int u = c.u;
    u += 0x7FFFu + ((u >> 16) & 1u);   // RNE
    return (unsigned short)(u >> 16);
}
static __device__ __forceinline__ float bf16lo_to_f32(unsigned int v) {
    union { unsigned int u; float f; } c; c.u = v << 16; return c.f;
}
static __device__ __forceinline__ float bf16hi_to_f32(unsigned int v) {
    union { unsigned int u; float f; } c; c.u = v & 0xFFFF0000u; return c.f;
}

// ONE setup kernel, three independent block roles (partition first — critical path):
//  [0, PBLKS):            chunk-local partition into fixed-capacity bucket regions
//  [PBLKS, +CONV_BLKS):   x f32 -> bf16
//  [+, +WPACK_BLKS):      weight pack (MFMA B-fragment order) + combined bias
__global__ void setup_partition_kernel(const float* __restrict__ x, const int* __restrict__ ei,
                                       const float* __restrict__ w_self, const float* __restrict__ b_self,
                                       const float* __restrict__ w_neigh, const float* __restrict__ b_neigh,
                                       unsigned short* __restrict__ xb, unsigned short* __restrict__ w_swz,
                                       float* __restrict__ bias, int* __restrict__ gcur,
                                       int* __restrict__ ovfc, unsigned int* __restrict__ csr,
                                       unsigned int* __restrict__ ovf,
                                       int n4, int E, int NB, int PBLKS) {
    int b = blockIdx.x, t = threadIdx.x;
    if (b < PBLKS) {
        __shared__ int hist[NBMAX];
        __shared__ int base[NBMAX];
        __shared__ int avail[NBMAX];
        __shared__ int obase[NBMAX];
        __shared__ int lcur[NBMAX];
        int cbase = b * PCH;
        int cend = min(E, cbase + PCH);
        for (int i = t; i < NB; i += NT) { hist[i] = 0; lcur[i] = 0; }
        __syncthreads();
        for (int e = cbase + t; e < cend; e += NT)
            atomicAdd(&hist[ei[E + e] >> 6], 1);
        __syncthreads();
        for (int bk = t; bk < NB; bk += NT) {
            int c = hist[bk];
            if (c) {
                int r = atomicAdd(&gcur[bk], c);
                int av = (r < CAPB) ? min(c, CAPB - r) : 0;
                base[bk] = r;
                avail[bk] = av;
                obase[bk] = (c > av) ? atomicAdd(ovfc, c - av) : 0;
            }
        }
        __syncthreads();
        for (int e = cbase + t; e < cend; e += NT) {
            unsigned int src = (unsigned int)ei[e];
            unsigned int dst = (unsigned int)ei[E + e];
            int bk = (int)(dst >> 6);
            int idx = atomicAdd(&lcur[bk], 1);
            unsigned int pk = (dst << 16) | src;
            if (idx < avail[bk]) csr[(size_t)bk * CAPB + base[bk] + idx] = pk;
            else ovf[obase[bk] + idx - avail[bk]] = pk;
        }
    } else if (b < PBLKS + CONV_BLKS) {
        for (int g = (b - PBLKS) * NT + t; g < n4; g += CONV_BLKS * NT) {
            float4 v = reinterpret_cast<const float4*>(x)[g];
            ushort4 s = make_ushort4(f32_to_bf16(v.x), f32_to_bf16(v.y),
                                     f32_to_bf16(v.z), f32_to_bf16(v.w));
            reinterpret_cast<ushort4*>(xb)[g] = s;
        }
    } else {
        int g = (b - PBLKS - CONV_BLKS) * NT + t;   // 4096 slots
        if (g < 128) bias[g] = b_self[g] + b_neigh[g];
        if (g >= 64 * 64) return;
        int f = g >> 6, l = g & 63;
        int ks = f >> 3, nf = f & 7;
        int j = nf * 16 + (l & 15);
        int kbase = ks * 32 + ((l >> 4) << 3);
#pragma unroll
        for (int e = 0; e < 8; ++e) {
            int k = kbase + e;
            float v = (k < 128) ? w_self[(size_t)j * 128 + k]
                                : w_neigh[(size_t)j * 128 + (k - 128)];
            w_swz[((size_t)g << 3) + e] = f32_to_bf16(v);
        }
    }
}

// FUSED aggregate + finalize. One block per bucket (= 64 output rows).
// csr region at fixed base b*CAPB holding min(count, CAPB) edges; overflow list
// (normally empty) scanned per node. Counting-sort by local dst (ushort srt),
// then wave w accumulates nodes 8w..8w+7: one dwordx4 gathers 4 edges
// (16 lanes x 16B per 256B row), 16 edges in flight, 2 shfl_xor reduce,
// mean -> A-tile, 8-wave MFMA epilogue. LDS ~38KB -> 4 blocks/CU.
__global__ void __launch_bounds__(BAT)
fused_aggregate_kernel(const unsigned short* __restrict__ xb,
                       const int* __restrict__ gcur,
                       const int* __restrict__ ovfc,
                       const unsigned int* __restrict__ csr,
                       const unsigned int* __restrict__ ovf,
                       const unsigned short* __restrict__ w_swz,
                       const float* __restrict__ bias,
                       float* __restrict__ out, int n) {
    __shared__ unsigned short srt[CAPB];       // sorted src ids (4KB)
    __shared__ unsigned short xm[BUCK][264];   // [x(128) | mean(128)] bf16 (33.8KB)
    __shared__ int bin[BUCK];
    __shared__ int boff_s[BUCK + 1];
    __shared__ int cur[BUCK];

    int tid = threadIdx.x, wid = tid >> 6, lane = tid & 63;
    int grp = lane >> 4, j = lane & 15;     // 4 groups of 16 lanes
    int b0 = blockIdx.x;
    int bsize = min(gcur[b0], CAPB);
    int ovfn = ovfc[0];
    const unsigned int* my = csr + (size_t)b0 * CAPB;
    int gbase = b0 * BUCK;
    const uint4* x16 = reinterpret_cast<const uint4*>(xb);   // 16 uint4 per row

    // Stage x rows into A-tile x-part (coalesced).
    for (int fi = tid; fi < BUCK * 16; fi += BAT) {
        int row = fi >> 4, c = fi & 15;
        int grow = gbase + row;
        ushort8 s = (ushort8)0;
        if (grow < n) s = reinterpret_cast<const ushort8*>(xb + (size_t)grow * DIM)[c];
        *reinterpret_cast<ushort8*>(&xm[row][c * 8]) = s;
    }

    // ---- counting sort by local dst ----
    for (int i = tid; i < BUCK; i += BAT) bin[i] = 0;
    __syncthreads();
    for (int i = tid; i < bsize; i += BAT)
        atomicAdd(&bin[(my[i] >> 16) & 63], 1);
    __syncthreads();
    if (wid == 0) {   // wave-0 shuffle scan of 64 bins
        int v = bin[lane];
        int s = v;
        for (int d = 1; d < 64; d <<= 1) {
            int u = __shfl_up(s, d, 64);
            if (lane >= d) s += u;
        }
        boff_s[lane] = s - v;
        cur[lane] = s - v;
        if (lane == 63) boff_s[64] = s;
    }
    __syncthreads();
    for (int i = tid; i < bsize; i += BAT) {
        unsigned int p = my[i];
        int d = (p >> 16) & 63;
        srt[atomicAdd(&cur[d], 1)] = (unsigned short)(p & 0xFFFFu);
    }
    __syncthreads();

    // ---- per-node gather, 4 edges/instr, 16 edges in flight ----
#pragma unroll 2
    for (int i = 0; i < 8; ++i) {
        int nd = wid * 8 + i;
        int s = boff_s[nd], epd = boff_s[nd + 1];
        float acc[8];
#pragma unroll
        for (int k = 0; k < 8; ++k) acc[k] = 0.f;
        for (int e = s; e < epd; e += 16) {
            uint4 v[4];
#pragma unroll
            for (int q = 0; q < 4; ++q) {
                int eidx = e + q * 4 + grp;
                bool ok = eidx < epd;
                int src = srt[ok ? eidx : s];
                uint4 tv = x16[(size_t)src * 16 + j];
                if (!ok) tv = (uint4){0u, 0u, 0u, 0u};
                v[q] = tv;
            }
#pragma unroll
            for (int q = 0; q < 4; ++q) {
                acc[0] += bf16lo_to_f32(v[q].x); acc[1] += bf16hi_to_f32(v[q].x);
                acc[2] += bf16lo_to_f32(v[q].y); acc[3] += bf16hi_to_f32(v[q].y);
                acc[4] += bf16lo_to_f32(v[q].z); acc[5] += bf16hi_to_f32(v[q].z);
                acc[6] += bf16lo_to_f32(v[q].w); acc[7] += bf16hi_to_f32(v[q].w);
            }
        }
        int deg = epd - s;
        // Overflow edges (normally ovfn == 0).
        for (int o = 0; o < ovfn; ++o) {
            unsigned int p = ovf[o];
            if ((int)(p >> 16) == gbase + nd) {
                uint4 v = x16[(size_t)(p & 0xFFFFu) * 16 + j];
                acc[0] += bf16lo_to_f32(v.x); acc[1] += bf16hi_to_f32(v.x);
                acc[2] += bf16lo_to_f32(v.y); acc[3] += bf16hi_to_f32(v.y);
                acc[4] += bf16lo_to_f32(v.z); acc[5] += bf16hi_to_f32(v.z);
                acc[6] += bf16lo_to_f32(v.w); acc[7] += bf16hi_to_f32(v.w);
                ++deg;
            }
        }
        // cross-group reduce: sum the 4 lane-groups (same col set each).
#pragma unroll
        for (int k = 0; k < 8; ++k) {
            acc[k] += __shfl_xor(acc[k], 16);
            acc[k] += __shfl_xor(acc[k], 32);
        }
        float inv = deg > 0 ? 1.0f / (float)deg : 0.f;
        if (grp == 0) {
            ushort8 m = (ushort8)0;
#pragma unroll
            for (int k = 0; k < 8; ++k) m[k] = f32_to_bf16(acc[k] * inv);
            *reinterpret_cast<ushort8*>(&xm[nd][128 + j * 8]) = m;
        }
    }
    __syncthreads();

    // ---- MFMA epilogue: wave = 16-row x 64-col quadrant ----
    int rg = wid >> 1, ch = wid & 1;
    int arow = rg * 16 + (lane & 15);
    int koff = (lane >> 4) << 3;

    f32x4 acc[4];
#pragma unroll
    for (int nf = 0; nf < 4; ++nf) acc[nf] = (f32x4){0.f, 0.f, 0.f, 0.f};

#pragma unroll
    for (int ks = 0; ks < 8; ++ks) {
        short8 a = *reinterpret_cast<const short8*>(&xm[arow][ks * 32 + koff]);
#pragma unroll
        for (int nf = 0; nf < 4; ++nf) {
            int f = ks * 8 + ch * 4 + nf;
            short8 b = *reinterpret_cast<const short8*>(w_swz + (((size_t)f * 64 + lane) << 3));
            acc[nf] = __builtin_amdgcn_mfma_f32_16x16x32_bf16(a, b, acc[nf], 0, 0, 0);
        }
    }

    int crow0 = rg * 16 + ((lane >> 4) << 2);
#pragma unroll
    for (int nf = 0; nf < 4; ++nf) {
        int col = (ch * 4 + nf) * 16 + (lane & 15);
        float bs = bias[col];
#pragma unroll
        for (int r = 0; r < 4; ++r) {
            int grow = gbase + crow0 + r;
            if (grow < n) out[(size_t)grow * DIM + col] = acc[nf][r] + bs;
        }
    }
}

extern "C" void kernel_launch(void* const* d_in, const int* in_sizes, int n_in,
                              void* d_out, int out_size, void* d_ws, size_t ws_size,
                              hipStream_t stream) {
    const float* x       = (const float*)d_in[0];
    const int*   ei      = (const int*)d_in[1];
    const float* w_self  = (const float*)d_in[2];
    const float* b_self  = (const float*)d_in[3];
    const float* w_neigh = (const float*)d_in[4];
    const float* b_neigh = (const float*)d_in[5];
    float* out = (float*)d_out;

    int n = in_sizes[0] / DIM;
    int E = in_sizes[1] / 2;
    int NB = (n + BUCK - 1) / BUCK;   // 782 for n=50000; requires NB <= NBMAX

    // ws: gcur[NBMAX] | ovfc[4] | csr uint[NB*CAPB] (~6.4MB) | ovf uint[E] (~3.2MB) |
    //     (align16) w_swz bf16[32768] | bias f32[128] | x_bf bf16[n*128] (~12.8MB)
    int* gcur = (int*)d_ws;
    int* ovfc = gcur + NBMAX;
    unsigned int* csr = (unsigned int*)(ovfc + 4);
    unsigned int* ovf = csr + (size_t)NB * CAPB;
    unsigned short* w_swz = (unsigned short*)(((uintptr_t)(ovf + E) + 15) & ~(uintptr_t)15);
    float* bias = (float*)(w_swz + 64 * 64 * 8);
    unsigned short* x_bf = (unsigned short*)(bias + 128);

    hipMemsetAsync(gcur, 0, (NBMAX + 4) * sizeof(int), stream);

    int n4 = n * DIM / 4;
    int PBLKS = (E + PCH - 1) / PCH;   // 98
    setup_partition_kernel<<<PBLKS + CONV_BLKS + WPACK_BLKS, NT, 0, stream>>>(
        x, ei, w_self, b_self, w_neigh, b_neigh, x_bf, w_swz, bias,
        gcur, ovfc, csr, ovf, n4, E, NB, PBLKS);

    fused_aggregate_kernel<<<NB, BAT, 0, stream>>>(x_bf, gcur, ovfc, csr, ovf,
                                                   w_swz, bias, out, n);
}

// Round 12
// 77.264 us; speedup vs baseline: 9.8667x; 1.1152x over previous
//
#include <hip/hip_runtime.h>

#define DIM 128
#define NT 256
#define BUCK 32          // dst nodes per bucket == MFMA tile rows
#define PCH 4096         // edges per partition chunk
#define NBMAX 2048       // max buckets (n <= 65536)
#define BAT 256          // threads in fused aggregate (4 waves x 8 nodes)
#define CAPB 1024        // fixed csr slots per bucket (avg 512, max ~640; overflow-safe)
#define CONV_BLKS 512
#define WPACK_BLKS 16

typedef __attribute__((ext_vector_type(8))) short short8;
typedef __attribute__((ext_vector_type(8))) unsigned short ushort8;
typedef __attribute__((ext_vector_type(4))) float f32x4;

static __device__ __forceinline__ unsigned short f32_to_bf16(float f) {
    union { float f; unsigned int u; } c; c.f = f;
    unsigned int u = c.u;
    u += 0x7FFFu + ((u >> 16) & 1u);   // RNE
    return (unsigned short)(u >> 16);
}
static __device__ __forceinline__ float bf16lo_to_f32(unsigned int v) {
    union { unsigned int u; float f; } c; c.u = v << 16; return c.f;
}
static __device__ __forceinline__ float bf16hi_to_f32(unsigned int v) {
    union { unsigned int u; float f; } c; c.u = v & 0xFFFF0000u; return c.f;
}

// ONE setup kernel, three independent block roles:
//  [0, PBLKS):            chunk-local partition into fixed-capacity bucket regions
//  [PBLKS, +CONV_BLKS):   x f32 -> bf16
//  [+, +WPACK_BLKS):      weight pack (MFMA B-fragment order) + combined bias
__global__ void setup_partition_kernel(const float* __restrict__ x, const int* __restrict__ ei,
                                       const float* __restrict__ w_self, const float* __restrict__ b_self,
                                       const float* __restrict__ w_neigh, const float* __restrict__ b_neigh,
                                       unsigned short* __restrict__ xb, unsigned short* __restrict__ w_swz,
                                       float* __restrict__ bias, int* __restrict__ gcur,
                                       int* __restrict__ ovfc, unsigned int* __restrict__ csr,
                                       unsigned int* __restrict__ ovf,
                                       int n4, int E, int NB, int PBLKS) {
    int b = blockIdx.x, t = threadIdx.x;
    if (b < PBLKS) {
        __shared__ int hist[NBMAX];
        __shared__ int base[NBMAX];
        __shared__ int avail[NBMAX];
        __shared__ int obase[NBMAX];
        __shared__ int lcur[NBMAX];
        int cbase = b * PCH;
        int cend = min(E, cbase + PCH);
        for (int i = t; i < NB; i += NT) { hist[i] = 0; lcur[i] = 0; }
        __syncthreads();
        for (int e = cbase + t; e < cend; e += NT)
            atomicAdd(&hist[ei[E + e] >> 5], 1);
        __syncthreads();
        for (int bk = t; bk < NB; bk += NT) {
            int c = hist[bk];
            if (c) {
                int r = atomicAdd(&gcur[bk], c);
                int av = (r < CAPB) ? min(c, CAPB - r) : 0;
                base[bk] = r;
                avail[bk] = av;
                obase[bk] = (c > av) ? atomicAdd(ovfc, c - av) : 0;
            }
        }
        __syncthreads();
        for (int e = cbase + t; e < cend; e += NT) {
            unsigned int src = (unsigned int)ei[e];
            unsigned int dst = (unsigned int)ei[E + e];
            int bk = (int)(dst >> 5);
            int idx = atomicAdd(&lcur[bk], 1);
            unsigned int pk = (dst << 16) | src;
            if (idx < avail[bk]) csr[(size_t)bk * CAPB + base[bk] + idx] = pk;
            else ovf[obase[bk] + idx - avail[bk]] = pk;
        }
    } else if (b < PBLKS + CONV_BLKS) {
        for (int g = (b - PBLKS) * NT + t; g < n4; g += CONV_BLKS * NT) {
            float4 v = reinterpret_cast<const float4*>(x)[g];
            ushort4 s = make_ushort4(f32_to_bf16(v.x), f32_to_bf16(v.y),
                                     f32_to_bf16(v.z), f32_to_bf16(v.w));
            reinterpret_cast<ushort4*>(xb)[g] = s;
        }
    } else {
        int g = (b - PBLKS - CONV_BLKS) * NT + t;   // 4096 slots
        if (g < 128) bias[g] = b_self[g] + b_neigh[g];
        if (g >= 64 * 64) return;
        int f = g >> 6, l = g & 63;
        int ks = f >> 3, nf = f & 7;
        int j = nf * 16 + (l & 15);
        int kbase = ks * 32 + ((l >> 4) << 3);
#pragma unroll
        for (int e = 0; e < 8; ++e) {
            int k = kbase + e;
            float v = (k < 128) ? w_self[(size_t)j * 128 + k]
                                : w_neigh[(size_t)j * 128 + (k - 128)];
            w_swz[((size_t)g << 3) + e] = f32_to_bf16(v);
        }
    }
}

// FUSED aggregate + finalize. One block per bucket (= 32 output rows), 4 waves.
// LDS ~19.4KB -> 8 blocks/CU (32 waves, 100% theoretical occupancy).
// Counting-sort by local dst (ushort srt), wave w owns nodes 8w..8w+7:
// one dwordx4 gathers 4 edges (16 lanes x 16B per 256B row), 16 edges in
// flight, 2 shfl_xor reduce, mean -> A-tile, 4-wave MFMA epilogue.
__global__ void __launch_bounds__(BAT)
fused_aggregate_kernel(const unsigned short* __restrict__ xb,
                       const int* __restrict__ gcur,
                       const int* __restrict__ ovfc,
                       const unsigned int* __restrict__ csr,
                       const unsigned int* __restrict__ ovf,
                       const unsigned short* __restrict__ w_swz,
                       const float* __restrict__ bias,
                       float* __restrict__ out, int n) {
    __shared__ unsigned short srt[CAPB];       // sorted src ids (2KB)
    __shared__ unsigned short xm[BUCK][264];   // [x(128) | mean(128)] bf16 (16.9KB)
    __shared__ int bin[BUCK];
    __shared__ int boff_s[BUCK + 1];
    __shared__ int cur[BUCK];

    int tid = threadIdx.x, wid = tid >> 6, lane = tid & 63;
    int grp = lane >> 4, j = lane & 15;     // 4 groups of 16 lanes
    int b0 = blockIdx.x;
    int bsize = min(gcur[b0], CAPB);
    int ovfn = ovfc[0];
    const unsigned int* my = csr + (size_t)b0 * CAPB;
    int gbase = b0 * BUCK;
    const uint4* x16 = reinterpret_cast<const uint4*>(xb);   // 16 uint4 per row

    // Stage x rows into A-tile x-part (coalesced).
    for (int fi = tid; fi < BUCK * 16; fi += BAT) {
        int row = fi >> 4, c = fi & 15;
        int grow = gbase + row;
        ushort8 s = (ushort8)0;
        if (grow < n) s = reinterpret_cast<const ushort8*>(xb + (size_t)grow * DIM)[c];
        *reinterpret_cast<ushort8*>(&xm[row][c * 8]) = s;
    }

    // ---- counting sort by local dst (32 bins) ----
    for (int i = tid; i < BUCK; i += BAT) bin[i] = 0;
    __syncthreads();
    for (int i = tid; i < bsize; i += BAT)
        atomicAdd(&bin[(my[i] >> 16) & 31], 1);
    __syncthreads();
    if (wid == 0) {   // wave-0 shuffle scan of 32 bins
        int v = (lane < BUCK) ? bin[lane] : 0;
        int s = v;
        for (int d = 1; d < BUCK; d <<= 1) {
            int u = __shfl_up(s, d, 64);
            if (lane >= d) s += u;
        }
        if (lane < BUCK) {
            boff_s[lane] = s - v;
            cur[lane] = s - v;
            if (lane == BUCK - 1) boff_s[BUCK] = s;
        }
    }
    __syncthreads();
    for (int i = tid; i < bsize; i += BAT) {
        unsigned int p = my[i];
        int d = (p >> 16) & 31;
        srt[atomicAdd(&cur[d], 1)] = (unsigned short)(p & 0xFFFFu);
    }
    __syncthreads();

    // ---- per-node gather, 4 edges/instr, 16 edges in flight ----
#pragma unroll 2
    for (int i = 0; i < 8; ++i) {
        int nd = wid * 8 + i;
        int s = boff_s[nd], epd = boff_s[nd + 1];
        float acc[8];
#pragma unroll
        for (int k = 0; k < 8; ++k) acc[k] = 0.f;
        for (int e = s; e < epd; e += 16) {
            uint4 v[4];
#pragma unroll
            for (int q = 0; q < 4; ++q) {
                int eidx = e + q * 4 + grp;
                bool ok = eidx < epd;
                int src = srt[ok ? eidx : s];
                uint4 tv = x16[(size_t)src * 16 + j];
                if (!ok) tv = (uint4){0u, 0u, 0u, 0u};
                v[q] = tv;
            }
#pragma unroll
            for (int q = 0; q < 4; ++q) {
                acc[0] += bf16lo_to_f32(v[q].x); acc[1] += bf16hi_to_f32(v[q].x);
                acc[2] += bf16lo_to_f32(v[q].y); acc[3] += bf16hi_to_f32(v[q].y);
                acc[4] += bf16lo_to_f32(v[q].z); acc[5] += bf16hi_to_f32(v[q].z);
                acc[6] += bf16lo_to_f32(v[q].w); acc[7] += bf16hi_to_f32(v[q].w);
            }
        }
        int deg = epd - s;
        // Overflow edges (normally ovfn == 0).
        for (int o = 0; o < ovfn; ++o) {
            unsigned int p = ovf[o];
            if ((int)(p >> 16) == gbase + nd) {
                uint4 v = x16[(size_t)(p & 0xFFFFu) * 16 + j];
                acc[0] += bf16lo_to_f32(v.x); acc[1] += bf16hi_to_f32(v.x);
                acc[2] += bf16lo_to_f32(v.y); acc[3] += bf16hi_to_f32(v.y);
                acc[4] += bf16lo_to_f32(v.z); acc[5] += bf16hi_to_f32(v.z);
                acc[6] += bf16lo_to_f32(v.w); acc[7] += bf16hi_to_f32(v.w);
                ++deg;
            }
        }
        // cross-group reduce: sum the 4 lane-groups (same col set each).
#pragma unroll
        for (int k = 0; k < 8; ++k) {
            acc[k] += __shfl_xor(acc[k], 16);
            acc[k] += __shfl_xor(acc[k], 32);
        }
        float inv = deg > 0 ? 1.0f / (float)deg : 0.f;
        if (grp == 0) {
            ushort8 m = (ushort8)0;
#pragma unroll
            for (int k = 0; k < 8; ++k) m[k] = f32_to_bf16(acc[k] * inv);
            *reinterpret_cast<ushort8*>(&xm[nd][128 + j * 8]) = m;
        }
    }
    __syncthreads();

    // ---- MFMA epilogue: 4 waves, wave = 16-row x 64-col quadrant ----
    int rg = wid >> 1, ch = wid & 1;
    int arow = rg * 16 + (lane & 15);
    int koff = (lane >> 4) << 3;

    f32x4 acc[4];
#pragma unroll
    for (int nf = 0; nf < 4; ++nf) acc[nf] = (f32x4){0.f, 0.f, 0.f, 0.f};

#pragma unroll
    for (int ks = 0; ks < 8; ++ks) {
        short8 a = *reinterpret_cast<const short8*>(&xm[arow][ks * 32 + koff]);
#pragma unroll
        for (int nf = 0; nf < 4; ++nf) {
            int f = ks * 8 + ch * 4 + nf;
            short8 b = *reinterpret_cast<const short8*>(w_swz + (((size_t)f * 64 + lane) << 3));
            acc[nf] = __builtin_amdgcn_mfma_f32_16x16x32_bf16(a, b, acc[nf], 0, 0, 0);
        }
    }

    int crow0 = rg * 16 + ((lane >> 4) << 2);
#pragma unroll
    for (int nf = 0; nf < 4; ++nf) {
        int col = (ch * 4 + nf) * 16 + (lane & 15);
        float bs = bias[col];
#pragma unroll
        for (int r = 0; r < 4; ++r) {
            int grow = gbase + crow0 + r;
            if (grow < n) out[(size_t)grow * DIM + col] = acc[nf][r] + bs;
        }
    }
}

extern "C" void kernel_launch(void* const* d_in, const int* in_sizes, int n_in,
                              void* d_out, int out_size, void* d_ws, size_t ws_size,
                              hipStream_t stream) {
    const float* x       = (const float*)d_in[0];
    const int*   ei      = (const int*)d_in[1];
    const float* w_self  = (const float*)d_in[2];
    const float* b_self  = (const float*)d_in[3];
    const float* w_neigh = (const float*)d_in[4];
    const float* b_neigh = (const float*)d_in[5];
    float* out = (float*)d_out;

    int n = in_sizes[0] / DIM;
    int E = in_sizes[1] / 2;
    int NB = (n + BUCK - 1) / BUCK;   // 1563 for n=50000; requires NB <= NBMAX

    // ws: gcur[NBMAX] | ovfc[4] | csr uint[NB*CAPB] (~6.4MB) | ovf uint[E] (~3.2MB) |
    //     (align16) w_swz bf16[32768] | bias f32[128] | x_bf bf16[n*128] (~12.8MB)
    int* gcur = (int*)d_ws;
    int* ovfc = gcur + NBMAX;
    unsigned int* csr = (unsigned int*)(ovfc + 4);
    unsigned int* ovf = csr + (size_t)NB * CAPB;
    unsigned short* w_swz = (unsigned short*)(((uintptr_t)(ovf + E) + 15) & ~(uintptr_t)15);
    float* bias = (float*)(w_swz + 64 * 64 * 8);
    unsigned short* x_bf = (unsigned short*)(bias + 128);

    hipMemsetAsync(gcur, 0, (NBMAX + 4) * sizeof(int), stream);

    int n4 = n * DIM / 4;
    int PBLKS = (E + PCH - 1) / PCH;   // 196
    setup_partition_kernel<<<PBLKS + CONV_BLKS + WPACK_BLKS, NT, 0, stream>>>(
        x, ei, w_self, b_self, w_neigh, b_neigh, x_bf, w_swz, bias,
        gcur, ovfc, csr, ovf, n4, E, NB, PBLKS);

    fused_aggregate_kernel<<<NB, BAT, 0, stream>>>(x_bf, gcur, ovfc, csr, ovf,
                                                   w_swz, bias, out, n);
}

// Round 13
// 72.988 us; speedup vs baseline: 10.4447x; 1.0586x over previous
//
#include <hip/hip_runtime.h>

#define DIM 128
#define NT 256
#define BUCK 32          // dst nodes per bucket == MFMA tile rows
#define PCH 4096         // edges per partition chunk
#define NBMAX 2048       // max buckets (n <= 65536)
#define BAT 256          // threads in fused aggregate (4 waves x 8 nodes)
#define CAPB 1024        // fixed csr slots per bucket (avg 512, max ~640; overflow-safe)
#define CONV_BLKS 512
#define WPACK_BLKS 16

typedef __attribute__((ext_vector_type(8))) short short8;
typedef __attribute__((ext_vector_type(8))) unsigned short ushort8;
typedef __attribute__((ext_vector_type(4))) float f32x4;
typedef __attribute__((ext_vector_type(2))) float f32x2;

static __device__ __forceinline__ unsigned short f32_to_bf16(float f) {
    union { float f; unsigned int u; } c; c.f = f;
    unsigned int u = c.u;
    u += 0x7FFFu + ((u >> 16) & 1u);   // RNE
    return (unsigned short)(u >> 16);
}

// ONE setup kernel, three independent block roles:
//  [0, PBLKS):            chunk-local partition into fixed-capacity bucket regions
//  [PBLKS, +CONV_BLKS):   x f32 -> bf16 table AND fp8(e4m3) gather table
//  [+, +WPACK_BLKS):      weight pack (MFMA B-fragment order) + combined bias
__global__ void setup_partition_kernel(const float* __restrict__ x, const int* __restrict__ ei,
                                       const float* __restrict__ w_self, const float* __restrict__ b_self,
                                       const float* __restrict__ w_neigh, const float* __restrict__ b_neigh,
                                       unsigned short* __restrict__ xb, unsigned int* __restrict__ xf8,
                                       unsigned short* __restrict__ w_swz,
                                       float* __restrict__ bias, int* __restrict__ gcur,
                                       int* __restrict__ ovfc, unsigned int* __restrict__ csr,
                                       unsigned int* __restrict__ ovf,
                                       int n4, int E, int NB, int PBLKS) {
    int b = blockIdx.x, t = threadIdx.x;
    if (b < PBLKS) {
        __shared__ int hist[NBMAX];
        __shared__ int base[NBMAX];
        __shared__ int avail[NBMAX];
        __shared__ int obase[NBMAX];
        __shared__ int lcur[NBMAX];
        int cbase = b * PCH;
        int cend = min(E, cbase + PCH);
        for (int i = t; i < NB; i += NT) { hist[i] = 0; lcur[i] = 0; }
        __syncthreads();
        for (int e = cbase + t; e < cend; e += NT)
            atomicAdd(&hist[ei[E + e] >> 5], 1);
        __syncthreads();
        for (int bk = t; bk < NB; bk += NT) {
            int c = hist[bk];
            if (c) {
                int r = atomicAdd(&gcur[bk], c);
                int av = (r < CAPB) ? min(c, CAPB - r) : 0;
                base[bk] = r;
                avail[bk] = av;
                obase[bk] = (c > av) ? atomicAdd(ovfc, c - av) : 0;
            }
        }
        __syncthreads();
        for (int e = cbase + t; e < cend; e += NT) {
            unsigned int src = (unsigned int)ei[e];
            unsigned int dst = (unsigned int)ei[E + e];
            int bk = (int)(dst >> 5);
            int idx = atomicAdd(&lcur[bk], 1);
            unsigned int pk = (dst << 16) | src;
            if (idx < avail[bk]) csr[(size_t)bk * CAPB + base[bk] + idx] = pk;
            else ovf[obase[bk] + idx - avail[bk]] = pk;
        }
    } else if (b < PBLKS + CONV_BLKS) {
        for (int g = (b - PBLKS) * NT + t; g < n4; g += CONV_BLKS * NT) {
            float4 v = reinterpret_cast<const float4*>(x)[g];
            ushort4 s = make_ushort4(f32_to_bf16(v.x), f32_to_bf16(v.y),
                                     f32_to_bf16(v.z), f32_to_bf16(v.w));
            reinterpret_cast<ushort4*>(xb)[g] = s;
            int p = __builtin_amdgcn_cvt_pk_fp8_f32(v.x, v.y, 0, false);   // bytes 0,1
            p = __builtin_amdgcn_cvt_pk_fp8_f32(v.z, v.w, p, true);        // bytes 2,3
            xf8[g] = (unsigned int)p;
        }
    } else {
        int g = (b - PBLKS - CONV_BLKS) * NT + t;   // 4096 slots
        if (g < 128) bias[g] = b_self[g] + b_neigh[g];
        if (g >= 64 * 64) return;
        int f = g >> 6, l = g & 63;
        int ks = f >> 3, nf = f & 7;
        int j = nf * 16 + (l & 15);
        int kbase = ks * 32 + ((l >> 4) << 3);
#pragma unroll
        for (int e = 0; e < 8; ++e) {
            int k = kbase + e;
            float v = (k < 128) ? w_self[(size_t)j * 128 + k]
                                : w_neigh[(size_t)j * 128 + (k - 128)];
            w_swz[((size_t)g << 3) + e] = f32_to_bf16(v);
        }
    }
}

// FUSED aggregate + finalize. One block per bucket (= 32 output rows), 4 waves.
// Gather table is fp8 e4m3 (128B/row): one dwordx2 per lane covers 8 cols,
// 16 lanes cover a row -> 4 edges per wave-instr, 16 edges in flight.
// HW decode via v_cvt_pk_f32_fp8. Mean (f32 acc) -> bf16 A-tile; self term and
// MFMA stay bf16. 2 shfl_xor reduce across lane-groups; 4-wave MFMA epilogue.
__global__ void __launch_bounds__(BAT)
fused_aggregate_kernel(const unsigned short* __restrict__ xb,
                       const unsigned int* __restrict__ xf8,
                       const int* __restrict__ gcur,
                       const int* __restrict__ ovfc,
                       const unsigned int* __restrict__ csr,
                       const unsigned int* __restrict__ ovf,
                       const unsigned short* __restrict__ w_swz,
                       const float* __restrict__ bias,
                       float* __restrict__ out, int n) {
    __shared__ unsigned short srt[CAPB];       // sorted src ids (2KB)
    __shared__ unsigned short xm[BUCK][264];   // [x(128) | mean(128)] bf16 (16.9KB)
    __shared__ int bin[BUCK];
    __shared__ int boff_s[BUCK + 1];
    __shared__ int cur[BUCK];

    int tid = threadIdx.x, wid = tid >> 6, lane = tid & 63;
    int grp = lane >> 4, j = lane & 15;     // 4 groups of 16 lanes
    int b0 = blockIdx.x;
    int bsize = min(gcur[b0], CAPB);
    int ovfn = ovfc[0];
    const unsigned int* my = csr + (size_t)b0 * CAPB;
    int gbase = b0 * BUCK;
    const uint2* x8 = reinterpret_cast<const uint2*>(xf8);   // 16 uint2 per fp8 row

    // Stage x rows into A-tile x-part (coalesced, bf16).
    for (int fi = tid; fi < BUCK * 16; fi += BAT) {
        int row = fi >> 4, c = fi & 15;
        int grow = gbase + row;
        ushort8 s = (ushort8)0;
        if (grow < n) s = reinterpret_cast<const ushort8*>(xb + (size_t)grow * DIM)[c];
        *reinterpret_cast<ushort8*>(&xm[row][c * 8]) = s;
    }

    // ---- counting sort by local dst (32 bins) ----
    for (int i = tid; i < BUCK; i += BAT) bin[i] = 0;
    __syncthreads();
    for (int i = tid; i < bsize; i += BAT)
        atomicAdd(&bin[(my[i] >> 16) & 31], 1);
    __syncthreads();
    if (wid == 0) {   // wave-0 shuffle scan of 32 bins
        int v = (lane < BUCK) ? bin[lane] : 0;
        int s = v;
        for (int d = 1; d < BUCK; d <<= 1) {
            int u = __shfl_up(s, d, 64);
            if (lane >= d) s += u;
        }
        if (lane < BUCK) {
            boff_s[lane] = s - v;
            cur[lane] = s - v;
            if (lane == BUCK - 1) boff_s[BUCK] = s;
        }
    }
    __syncthreads();
    for (int i = tid; i < bsize; i += BAT) {
        unsigned int p = my[i];
        int d = (p >> 16) & 31;
        srt[atomicAdd(&cur[d], 1)] = (unsigned short)(p & 0xFFFFu);
    }
    __syncthreads();

    // ---- per-node gather (fp8), 4 edges/instr, 16 edges in flight ----
#pragma unroll 2
    for (int i = 0; i < 8; ++i) {
        int nd = wid * 8 + i;
        int s = boff_s[nd], epd = boff_s[nd + 1];
        float acc[8];
#pragma unroll
        for (int k = 0; k < 8; ++k) acc[k] = 0.f;
        for (int e = s; e < epd; e += 16) {
            uint2 v[4];
#pragma unroll
            for (int q = 0; q < 4; ++q) {
                int eidx = e + q * 4 + grp;
                bool ok = eidx < epd;
                int src = srt[ok ? eidx : s];
                uint2 tv = x8[(size_t)src * 16 + j];
                if (!ok) tv = make_uint2(0u, 0u);   // fp8 0x00 == +0
                v[q] = tv;
            }
#pragma unroll
            for (int q = 0; q < 4; ++q) {
                f32x2 a0 = __builtin_amdgcn_cvt_pk_f32_fp8(v[q].x, false);
                f32x2 a1 = __builtin_amdgcn_cvt_pk_f32_fp8(v[q].x, true);
                f32x2 b0 = __builtin_amdgcn_cvt_pk_f32_fp8(v[q].y, false);
                f32x2 b1 = __builtin_amdgcn_cvt_pk_f32_fp8(v[q].y, true);
                acc[0] += a0.x; acc[1] += a0.y; acc[2] += a1.x; acc[3] += a1.y;
                acc[4] += b0.x; acc[5] += b0.y; acc[6] += b1.x; acc[7] += b1.y;
            }
        }
        int deg = epd - s;
        // Overflow edges (normally ovfn == 0).
        for (int o = 0; o < ovfn; ++o) {
            unsigned int p = ovf[o];
            if ((int)(p >> 16) == gbase + nd) {
                uint2 tv = x8[(size_t)(p & 0xFFFFu) * 16 + j];
                f32x2 a0 = __builtin_amdgcn_cvt_pk_f32_fp8(tv.x, false);
                f32x2 a1 = __builtin_amdgcn_cvt_pk_f32_fp8(tv.x, true);
                f32x2 b0 = __builtin_amdgcn_cvt_pk_f32_fp8(tv.y, false);
                f32x2 b1 = __builtin_amdgcn_cvt_pk_f32_fp8(tv.y, true);
                acc[0] += a0.x; acc[1] += a0.y; acc[2] += a1.x; acc[3] += a1.y;
                acc[4] += b0.x; acc[5] += b0.y; acc[6] += b1.x; acc[7] += b1.y;
                ++deg;
            }
        }
        // cross-group reduce: sum the 4 lane-groups (same 8-col set each).
#pragma unroll
        for (int k = 0; k < 8; ++k) {
            acc[k] += __shfl_xor(acc[k], 16);
            acc[k] += __shfl_xor(acc[k], 32);
        }
        float inv = deg > 0 ? 1.0f / (float)deg : 0.f;
        if (grp == 0) {
            ushort8 m = (ushort8)0;
#pragma unroll
            for (int k = 0; k < 8; ++k) m[k] = f32_to_bf16(acc[k] * inv);
            *reinterpret_cast<ushort8*>(&xm[nd][128 + j * 8]) = m;
        }
    }
    __syncthreads();

    // ---- MFMA epilogue: 4 waves, wave = 16-row x 64-col quadrant ----
    int rg = wid >> 1, ch = wid & 1;
    int arow = rg * 16 + (lane & 15);
    int koff = (lane >> 4) << 3;

    f32x4 acc[4];
#pragma unroll
    for (int nf = 0; nf < 4; ++nf) acc[nf] = (f32x4){0.f, 0.f, 0.f, 0.f};

#pragma unroll
    for (int ks = 0; ks < 8; ++ks) {
        short8 a = *reinterpret_cast<const short8*>(&xm[arow][ks * 32 + koff]);
#pragma unroll
        for (int nf = 0; nf < 4; ++nf) {
            int f = ks * 8 + ch * 4 + nf;
            short8 b = *reinterpret_cast<const short8*>(w_swz + (((size_t)f * 64 + lane) << 3));
            acc[nf] = __builtin_amdgcn_mfma_f32_16x16x32_bf16(a, b, acc[nf], 0, 0, 0);
        }
    }

    int crow0 = rg * 16 + ((lane >> 4) << 2);
#pragma unroll
    for (int nf = 0; nf < 4; ++nf) {
        int col = (ch * 4 + nf) * 16 + (lane & 15);
        float bs = bias[col];
#pragma unroll
        for (int r = 0; r < 4; ++r) {
            int grow = gbase + crow0 + r;
            if (grow < n) out[(size_t)grow * DIM + col] = acc[nf][r] + bs;
        }
    }
}

extern "C" void kernel_launch(void* const* d_in, const int* in_sizes, int n_in,
                              void* d_out, int out_size, void* d_ws, size_t ws_size,
                              hipStream_t stream) {
    const float* x       = (const float*)d_in[0];
    const int*   ei      = (const int*)d_in[1];
    const float* w_self  = (const float*)d_in[2];
    const float* b_self  = (const float*)d_in[3];
    const float* w_neigh = (const float*)d_in[4];
    const float* b_neigh = (const float*)d_in[5];
    float* out = (float*)d_out;

    int n = in_sizes[0] / DIM;
    int E = in_sizes[1] / 2;
    int NB = (n + BUCK - 1) / BUCK;   // 1563 for n=50000; requires NB <= NBMAX

    // ws: gcur[NBMAX] | ovfc[4] | csr uint[NB*CAPB] (~6.4MB) | ovf uint[E] (~3.2MB) |
    //     (align16) w_swz bf16[32768] | bias f32[128] | x_bf bf16[n*128] (~12.8MB) |
    //     x_fp8 uint[n*32] (~6.4MB)
    int* gcur = (int*)d_ws;
    int* ovfc = gcur + NBMAX;
    unsigned int* csr = (unsigned int*)(ovfc + 4);
    unsigned int* ovf = csr + (size_t)NB * CAPB;
    unsigned short* w_swz = (unsigned short*)(((uintptr_t)(ovf + E) + 15) & ~(uintptr_t)15);
    float* bias = (float*)(w_swz + 64 * 64 * 8);
    unsigned short* x_bf = (unsigned short*)(bias + 128);
    unsigned int* x_fp8 = (unsigned int*)(x_bf + (size_t)n * DIM);

    hipMemsetAsync(gcur, 0, (NBMAX + 4) * sizeof(int), stream);

    int n4 = n * DIM / 4;
    int PBLKS = (E + PCH - 1) / PCH;   // 196
    setup_partition_kernel<<<PBLKS + CONV_BLKS + WPACK_BLKS, NT, 0, stream>>>(
        x, ei, w_self, b_self, w_neigh, b_neigh, x_bf, x_fp8, w_swz, bias,
        gcur, ovfc, csr, ovf, n4, E, NB, PBLKS);

    fused_aggregate_kernel<<<NB, BAT, 0, stream>>>(x_bf, x_fp8, gcur, ovfc, csr, ovf,
                                                   w_swz, bias, out, n);
}